// Round 3
// baseline (6751.320 us; speedup 1.0000x reference)
//
#include <hip/hip_runtime.h>
#include <math.h>

#define BB 32
#define EE 512
#define VV 8192
#define TT 16
#define LL 4
#define FFD 2048
#define NHD 8
#define HDD 64
#define LDP 520   // padded LDS pitch (bf16 elems)
#define RWP 516   // padded LDS pitch (f32 elems) for raw/o2 scratch
#define EBP 1032  // padded LDS pitch (bf16) for embed panel (2064B rows, 16B aligned)
#define SCALE_EMB 22.627416997969522f
#define GRID_MEGA 128
#define NPH_STEP 15

typedef __attribute__((ext_vector_type(8))) short bf16x8;
typedef __attribute__((ext_vector_type(4))) float f32x4;
typedef unsigned long long ull;

__device__ __forceinline__ f32x4 mfma16(bf16x8 a, bf16x8 b, f32x4 c){
  return __builtin_amdgcn_mfma_f32_16x16x32_bf16(a, b, c, 0, 0, 0);
}

// ---------------- helpers ----------------
__device__ __forceinline__ float wave_sum(float v){
  for (int o = 32; o; o >>= 1) v += __shfl_down(v, o);
  return __shfl(v, 0);
}
__device__ __forceinline__ unsigned short f_to_bf(float f){
  unsigned u = __float_as_uint(f);
  unsigned r = (u + 0x7fffu + ((u >> 16) & 1u)) >> 16;
  return (unsigned short)r;
}
__device__ __forceinline__ float2 bf2_to_f2(const unsigned short* p){
  unsigned u = *(const unsigned*)p;
  float2 r;
  r.x = __uint_as_float(u << 16);
  r.y = __uint_as_float(u & 0xffff0000u);
  return r;
}

// coherent (cross-XCD) access primitives: bypass non-coherent per-XCD L2.
union UF { ull u; float f[2]; unsigned short s[4]; };
__device__ __forceinline__ ull ld_cv(const void* p){
  return __hip_atomic_load((const ull*)p, __ATOMIC_RELAXED, __HIP_MEMORY_SCOPE_AGENT);
}
__device__ __forceinline__ void st_cv(void* p, ull v){
  __hip_atomic_store((ull*)p, v, __ATOMIC_RELAXED, __HIP_MEMORY_SCOPE_AGENT);
}
__device__ __forceinline__ void upk2(ull u, float* f){ UF x; x.u = u; f[0] = x.f[0]; f[1] = x.f[1]; }
__device__ __forceinline__ ull pk2(float a, float b){ UF x; x.f[0] = a; x.f[1] = b; return x.u; }
__device__ __forceinline__ ull pkbf4(float a, float b, float c, float d){
  UF x; x.s[0] = f_to_bf(a); x.s[1] = f_to_bf(b); x.s[2] = f_to_bf(c); x.s[3] = f_to_bf(d); return x.u;
}

// ---- one-sided events: monotonic counter per phase instance (64B apart).
// Producer: drain stores -> syncthreads -> thread0 fetch_add.
// Consumer: thread0 spins until count == target -> syncthreads.
__device__ __forceinline__ void evt_post(unsigned* e){
  asm volatile("s_waitcnt vmcnt(0)" ::: "memory");
  __syncthreads();
  if (threadIdx.x == 0)
    __hip_atomic_fetch_add(e, 1u, __ATOMIC_RELAXED, __HIP_MEMORY_SCOPE_AGENT);
}
__device__ __forceinline__ void evt_wait(const unsigned* e, unsigned target){
  __syncthreads();
  if (threadIdx.x == 0){
    while (__hip_atomic_load(e, __ATOMIC_RELAXED, __HIP_MEMORY_SCOPE_AGENT) < target)
      __builtin_amdgcn_s_sleep(8);
  }
  __syncthreads();
  asm volatile("" ::: "memory");
}

// fp32 VALU GEMM core (kept for the one-off prologue kernels k_penc/k_pca)
__device__ __forceinline__ void gemm_chunk(const float* __restrict__ wrow0, int ldw,
    const unsigned short* xs, float* wt, float acc[4][2]){
  const int t = threadIdx.x, fg = t & 15, bg = t >> 4;
  #pragma unroll 1
  for (int c = 0; c < 8; ++c){
    const int k0 = c*64;
    __syncthreads();
    {
      int i = t*4;
      #pragma unroll
      for (int p = 0; p < 4; ++p, i += 1024){
        const int fr = i >> 6, kk = i & 63;
        float4 v = *(const float4*)(wrow0 + (size_t)fr*ldw + k0 + kk);
        wt[(kk+0)*68 + fr] = v.x;
        wt[(kk+1)*68 + fr] = v.y;
        wt[(kk+2)*68 + fr] = v.z;
        wt[(kk+3)*68 + fr] = v.w;
      }
    }
    __syncthreads();
    const unsigned short* xr0 = xs + (bg*2)*EE + k0;
    const unsigned short* xr1 = xr0 + EE;
    #pragma unroll 8
    for (int k = 0; k < 64; k += 2){
      float w0[4], w1[4];
      *(float4*)w0 = *(const float4*)(wt + (k+0)*68 + fg*4);
      *(float4*)w1 = *(const float4*)(wt + (k+1)*68 + fg*4);
      float2 xv0 = bf2_to_f2(xr0 + k);
      float2 xv1 = bf2_to_f2(xr1 + k);
      #pragma unroll
      for (int i = 0; i < 4; ++i){
        acc[i][0] += w0[i]*xv0.x + w1[i]*xv0.y;
        acc[i][1] += w0[i]*xv1.x + w1[i]*xv1.y;
      }
    }
  }
}

// Stage raw [B,E] f32 -> LDS bf16 (no LN), coherent loads, fully parallel.
__device__ __forceinline__ void stage_plain(unsigned short* xs, const float* __restrict__ xsrc){
  for (int i = threadIdx.x*4; i < BB*EE; i += 1024){
    ull u0 = ld_cv(xsrc + i);
    ull u1 = ld_cv(xsrc + i + 2);
    int r = i >> 9, c = i & 511;
    float f0[2], f1[2]; upk2(u0, f0); upk2(u1, f1);
    *(ull*)(xs + r*LDP + c) = pkbf4(f0[0], f0[1], f1[0], f1[1]);
  }
  __syncthreads();
}

// Stage [B,E] with pending LN: all 32 coherent loads issued upfront (registers),
// then per-row LN -> LDS bf16; optional LN'd f32 rows to xlnout (coherent).
__device__ __forceinline__ void stage_ln_reg(unsigned short* xs, const float* __restrict__ ybuf,
    const float* __restrict__ g, const float* __restrict__ bt, float* __restrict__ xlnout){
  const int lane = threadIdx.x & 63, wv = threadIdx.x >> 6;
  const int c0 = lane*4, c1 = 256 + lane*4;
  float ga[8], ba[8];
  #pragma unroll
  for (int k = 0; k < 4; ++k){ ga[k] = g[c0+k]; ga[4+k] = g[c1+k]; ba[k] = bt[c0+k]; ba[4+k] = bt[c1+k]; }
  ull a[8][4];
  #pragma unroll
  for (int j = 0; j < 8; ++j){
    const float* yr = ybuf + (size_t)(wv*8+j)*EE;
    a[j][0] = ld_cv(yr + c0); a[j][1] = ld_cv(yr + c0 + 2);
    a[j][2] = ld_cv(yr + c1); a[j][3] = ld_cv(yr + c1 + 2);
  }
  #pragma unroll
  for (int j = 0; j < 8; ++j){
    const int r = wv*8 + j;
    float v[8];
    upk2(a[j][0], v+0); upk2(a[j][1], v+2); upk2(a[j][2], v+4); upk2(a[j][3], v+6);
    float s = 0.f, s2 = 0.f;
    #pragma unroll
    for (int k = 0; k < 8; ++k){ s += v[k]; s2 += v[k]*v[k]; }
    s = wave_sum(s); s2 = wave_sum(s2);
    float m = s * (1.f/EE);
    float inv = rsqrtf(s2*(1.f/EE) - m*m + 1e-5f);
    float o_[8];
    #pragma unroll
    for (int k = 0; k < 8; ++k) o_[k] = (v[k]-m)*inv*ga[k] + ba[k];
    *(ull*)(xs + r*LDP + c0) = pkbf4(o_[0], o_[1], o_[2], o_[3]);
    *(ull*)(xs + r*LDP + c1) = pkbf4(o_[4], o_[5], o_[6], o_[7]);
    if (xlnout){
      st_cv(xlnout + (size_t)r*EE + c0,     pk2(o_[0], o_[1]));
      st_cv(xlnout + (size_t)r*EE + c0 + 2, pk2(o_[2], o_[3]));
      st_cv(xlnout + (size_t)r*EE + c1,     pk2(o_[4], o_[5]));
      st_cv(xlnout + (size_t)r*EE + c1 + 2, pk2(o_[6], o_[7]));
    }
  }
  __syncthreads();
}

// ---------------- prologue kernels ----------------

__global__ __launch_bounds__(256) void k_init(const float* __restrict__ special,
    float* __restrict__ dseq, float* __restrict__ x, unsigned* __restrict__ evt){
  int idx = blockIdx.x*256 + threadIdx.x;
  if (idx < BB*VV){
    int b = idx >> 13, v = idx & (VV-1);
    dseq[(size_t)b*((TT+1)*VV) + (size_t)TT*VV + v] = (v == 0) ? 1.f : 0.f;
  } else if (idx < BB*VV + BB*EE){
    int i = idx - BB*VV;
    x[i] = special[i & (EE-1)];
  } else {
    int i = idx - BB*VV - BB*EE;
    if (i < 4096) evt[i] = 0u;
  }
}

__global__ __launch_bounds__(256) void k_penc(const float* __restrict__ enc,
    const float* __restrict__ w, const float* __restrict__ bias, float* __restrict__ venc){
  __shared__ unsigned short xs[BB*EE];
  __shared__ float wt[64*68];
  const int l = blockIdx.x >> 3, et = blockIdx.x & 7;
  for (int i = threadIdx.x; i < BB*EE; i += 256) xs[i] = f_to_bf(enc[i]);
  const int t = threadIdx.x, fg = t & 15, bg = t >> 4;
  const int f0 = et*64;
  const float* wl = w + (size_t)l*3*EE*EE + (size_t)(2*EE + f0)*EE;
  const float* bl = bias + l*3*EE + 2*EE + f0;
  float acc[4][2];
  #pragma unroll
  for (int i = 0; i < 4; ++i){ float bv = bl[fg*4+i]; acc[i][0] = bv; acc[i][1] = bv; }
  gemm_chunk(wl, EE, xs, wt, acc);
  #pragma unroll
  for (int i = 0; i < 4; ++i)
    #pragma unroll
    for (int j = 0; j < 2; ++j)
      venc[(size_t)l*BB*EE + (bg*2+j)*EE + f0 + fg*4 + i] = acc[i][j];
}

__global__ __launch_bounds__(256) void k_pca(const float* __restrict__ venc,
    const float* __restrict__ w, const float* __restrict__ bias, float* __restrict__ cac){
  __shared__ unsigned short xs[BB*EE];
  __shared__ float wt[64*68];
  const int l = blockIdx.x >> 3, et = blockIdx.x & 7;
  const float* vin = venc + (size_t)l*BB*EE;
  for (int i = threadIdx.x; i < BB*EE; i += 256) xs[i] = f_to_bf(vin[i]);
  const int t = threadIdx.x, fg = t & 15, bg = t >> 4;
  const int f0 = et*64;
  const float* wl = w + (size_t)l*EE*EE + (size_t)f0*EE;
  const float* bl = bias + l*EE + f0;
  float acc[4][2];
  #pragma unroll
  for (int i = 0; i < 4; ++i){ float bv = bl[fg*4+i]; acc[i][0] = bv; acc[i][1] = bv; }
  gemm_chunk(wl, EE, xs, wt, acc);
  #pragma unroll
  for (int i = 0; i < 4; ++i)
    #pragma unroll
    for (int j = 0; j < 2; ++j)
      cac[(size_t)l*BB*EE + (bg*2+j)*EE + f0 + fg*4 + i] = acc[i][j];
}

__global__ __launch_bounds__(256) void k_cvt(const float* __restrict__ s,
    unsigned short* __restrict__ d, int n4){
  int i = blockIdx.x*256 + threadIdx.x;
  if (i < n4){
    float4 v = ((const float4*)s)[i];
    ushort4 o;
    o.x = f_to_bf(v.x); o.y = f_to_bf(v.y); o.z = f_to_bf(v.z); o.w = f_to_bf(v.w);
    ((ushort4*)d)[i] = o;
  }
}

__global__ __launch_bounds__(256) void k_embT(const float* __restrict__ emb,
    unsigned short* __restrict__ eT){
  __shared__ unsigned short tl[64][68];
  const int vt = blockIdx.x >> 3, et = blockIdx.x & 7;
  const int v0 = vt*64, e0 = et*64;
  for (int i = threadIdx.x; i < 64*64; i += 256){
    int vv = i >> 6, ee = i & 63;
    tl[vv][ee] = f_to_bf(emb[(size_t)(v0+vv)*EE + e0 + ee]);
  }
  __syncthreads();
  for (int i = threadIdx.x; i < 64*64; i += 256){
    int ee = i >> 6, vv = i & 63;
    eT[(size_t)(e0+ee)*VV + v0 + vv] = tl[vv][ee];
  }
}

// ---------------- mega-kernel phases ----------------

// A: qkv + attention for head h (8 blocks). xs/qs/att in LDS.
__device__ void ph_A(int h, unsigned short* xs, float* qs, float* att,
    const float* __restrict__ xsrc, const float* __restrict__ yprev,
    const float* __restrict__ lg, const float* __restrict__ lb, int use_ln,
    const unsigned short* __restrict__ Wb, const float* __restrict__ bias,
    float* __restrict__ kcl, float* __restrict__ vcl, float* __restrict__ xln,
    unsigned short* __restrict__ obf, int tpos, int tlen){
  if (use_ln) stage_ln_reg(xs, yprev, lg, lb, (h == 0) ? xln : nullptr);
  else        stage_plain(xs, xsrc);
  const int t = threadIdx.x, wv = t >> 6, lane = t & 63;
  const int lm = lane & 15, kg = lane >> 4;
  const unsigned short* b0r = xs + lm*LDP + kg*8;
  const unsigned short* b1r = xs + (lm+16)*LDP + kg*8;
  #pragma unroll
  for (int c = 0; c < 3; ++c){
    const int fbase = c*EE + h*64 + wv*16;
    const unsigned short* ar = Wb + (size_t)(fbase + lm)*EE + kg*8;
    f32x4 acc0 = {0.f,0.f,0.f,0.f}, acc1 = {0.f,0.f,0.f,0.f};
    #pragma unroll 4
    for (int ks = 0; ks < 16; ++ks){
      bf16x8 a  = *reinterpret_cast<const bf16x8*>(ar + ks*32);
      bf16x8 b0 = *reinterpret_cast<const bf16x8*>(b0r + ks*32);
      bf16x8 b1 = *reinterpret_cast<const bf16x8*>(b1r + ks*32);
      acc0 = mfma16(a, b0, acc0);
      acc1 = mfma16(a, b1, acc1);
    }
    #pragma unroll
    for (int r = 0; r < 4; ++r){
      const int frel = wv*16 + kg*4 + r;
      const float bv = bias[c*EE + h*64 + frel];
      float v0 = acc0[r] + bv, v1 = acc1[r] + bv;
      if (c == 0){
        qs[lm*68 + frel] = v0;
        qs[(lm+16)*68 + frel] = v1;
      } else if (c == 1){
        kcl[((lm*NHD + h)*TT + tpos)*HDD + frel] = v0;       // block-private
        kcl[(((lm+16)*NHD + h)*TT + tpos)*HDD + frel] = v1;
      } else {
        vcl[((lm*NHD + h)*TT + tpos)*HDD + frel] = v0;
        vcl[(((lm+16)*NHD + h)*TT + tpos)*HDD + frel] = v1;
      }
    }
  }
  __syncthreads();
  #pragma unroll
  for (int pp = 0; pp < 2; ++pp){
    const int p = t + pp*256;
    const int b = p >> 4, j = p & 15;
    if (j < tlen){
      const float* qrow = qs + b*68;
      const float* krow = kcl + ((b*NHD + h)*TT + j)*HDD;
      float a = 0.f;
      #pragma unroll
      for (int d = 0; d < HDD; d += 4){
        float4 qv = *(const float4*)(qrow + d);
        float4 kv = *(const float4*)(krow + d);
        a += qv.x*kv.x + qv.y*kv.y + qv.z*kv.z + qv.w*kv.w;
      }
      att[b*16 + j] = a*0.125f;
    }
  }
  __syncthreads();
  if (t < 32){
    const int b = t;
    float m = -1e30f;
    for (int j = 0; j < tlen; ++j) m = fmaxf(m, att[b*16 + j]);
    float s = 0.f;
    for (int j = 0; j < tlen; ++j) s += __expf(att[b*16 + j] - m);
    float inv = 1.f/s;
    for (int j = 0; j < tlen; ++j) att[b*16 + j] = __expf(att[b*16 + j] - m)*inv;
  }
  __syncthreads();
  {
    const int b = t >> 3, d0 = (t & 7)*8;
    float acc[8];
    #pragma unroll
    for (int i = 0; i < 8; ++i) acc[i] = 0.f;
    const float* vrow = vcl + ((b*NHD + h)*TT)*HDD + d0;
    for (int j = 0; j < tlen; ++j){
      const float a = att[b*16 + j];
      float4 v0 = *(const float4*)(vrow + j*HDD);
      float4 v1 = *(const float4*)(vrow + j*HDD + 4);
      acc[0] += a*v0.x; acc[1] += a*v0.y; acc[2] += a*v0.z; acc[3] += a*v0.w;
      acc[4] += a*v1.x; acc[5] += a*v1.y; acc[6] += a*v1.z; acc[7] += a*v1.w;
    }
    st_cv(obf + b*EE + h*HDD + d0,     pkbf4(acc[0], acc[1], acc[2], acc[3]));
    st_cv(obf + b*EE + h*HDD + d0 + 4, pkbf4(acc[4], acc[5], acc[6], acc[7]));
  }
}

// B: redundant out-projection (from obf) + residual + LN1(+cac) + LN2 + ffn1 GEMM.
// 32 blocks; block owns 64 H-features. block 0 also writes yacc base = LN2out + b2.
__device__ void ph_B(int blk, unsigned short* xs, float* rawf,
    const unsigned short* __restrict__ obf, const float* __restrict__ resid,
    const unsigned short* __restrict__ owb, const float* __restrict__ ob,
    const float* __restrict__ cac,
    const float* __restrict__ g1, const float* __restrict__ b1g,
    const float* __restrict__ g2, const float* __restrict__ b2g,
    const float* __restrict__ b2bias,
    const unsigned short* __restrict__ w1b, const float* __restrict__ b1bias,
    unsigned short* __restrict__ Hb, float* __restrict__ yacc){
  const int t = threadIdx.x;
  // stage obf (bf16 panel) -> xs
  for (int i = t*16; i < BB*EE; i += 4096){
    int r = i >> 9, c = i & 511;
    const unsigned short* s = obf + (size_t)r*EE + c;
    ull u0 = ld_cv(s), u1 = ld_cv(s+4), u2 = ld_cv(s+8), u3 = ld_cv(s+12);
    ull* dst = (ull*)(xs + r*LDP + c);
    dst[0] = u0; dst[1] = u1; dst[2] = u2; dst[3] = u3;
  }
  // stage resid f32 -> rawf
  for (int i = t*4; i < BB*EE; i += 1024){
    ull u0 = ld_cv(resid + i), u1 = ld_cv(resid + i + 2);
    int r = i >> 9, c = i & 511;
    float f0[2], f1[2]; upk2(u0, f0); upk2(u1, f1);
    rawf[r*RWP + c]     = f0[0]; rawf[r*RWP + c + 1] = f0[1];
    rawf[r*RWP + c + 2] = f1[0]; rawf[r*RWP + c + 3] = f1[1];
  }
  __syncthreads();
  // out-projection: wave wv covers f in [wv*128, wv*128+128)
  const int wv = t >> 6, lane = t & 63;
  const int lm = lane & 15, kg = lane >> 4;
  const unsigned short* b0r = xs + lm*LDP + kg*8;
  const unsigned short* b1r = xs + (lm+16)*LDP + kg*8;
  f32x4 acc[8][2];
  #pragma unroll
  for (int ft = 0; ft < 8; ++ft){
    const int f0 = wv*128 + ft*16;
    const unsigned short* ar = owb + (size_t)(f0 + lm)*EE + kg*8;
    f32x4 a0 = {0.f,0.f,0.f,0.f}, a1 = {0.f,0.f,0.f,0.f};
    #pragma unroll 4
    for (int ks = 0; ks < 16; ++ks){
      bf16x8 a  = *reinterpret_cast<const bf16x8*>(ar + ks*32);
      bf16x8 b0 = *reinterpret_cast<const bf16x8*>(b0r + ks*32);
      bf16x8 b1 = *reinterpret_cast<const bf16x8*>(b1r + ks*32);
      a0 = mfma16(a, b0, a0);
      a1 = mfma16(a, b1, a1);
    }
    acc[ft][0] = a0; acc[ft][1] = a1;
  }
  // epilogue: o2 = acc + ob + resid, written in place into rawf (per-lane slots)
  #pragma unroll
  for (int ft = 0; ft < 8; ++ft){
    const int fb = wv*128 + ft*16 + kg*4;
    #pragma unroll
    for (int r = 0; r < 4; ++r){
      const float bv = ob[fb + r];
      rawf[lm*RWP + fb + r]      = acc[ft][0][r] + bv + rawf[lm*RWP + fb + r];
      rawf[(lm+16)*RWP + fb + r] = acc[ft][1][r] + bv + rawf[(lm+16)*RWP + fb + r];
    }
  }
  __syncthreads();
  // LN1 (+cac) -> LN2 -> xs bf16; block0 writes yacc base = LN2out + b2
  {
    float* yi = (blk == 0) ? yacc : nullptr;
    const int c0 = lane*4, c1 = 256 + lane*4;
    for (int r = wv*8; r < wv*8 + 8; ++r){
      float v[8];
      *(float4*)(v+0) = *(const float4*)(rawf + r*RWP + c0);
      *(float4*)(v+4) = *(const float4*)(rawf + r*RWP + c1);
      float s = 0.f, s2 = 0.f;
      #pragma unroll
      for (int j = 0; j < 8; ++j){ s += v[j]; s2 += v[j]*v[j]; }
      s = wave_sum(s); s2 = wave_sum(s2);
      float m = s*(1.f/EE), inv = rsqrtf(s2*(1.f/EE) - m*m + 1e-5f);
      float4 ca0 = *(const float4*)(cac + (size_t)r*EE + c0);
      float4 ca1 = *(const float4*)(cac + (size_t)r*EE + c1);
      float nv[8]; float u = 0.f, u2 = 0.f;
      nv[0] = (v[0]-m)*inv*g1[c0+0] + b1g[c0+0] + ca0.x;
      nv[1] = (v[1]-m)*inv*g1[c0+1] + b1g[c0+1] + ca0.y;
      nv[2] = (v[2]-m)*inv*g1[c0+2] + b1g[c0+2] + ca0.z;
      nv[3] = (v[3]-m)*inv*g1[c0+3] + b1g[c0+3] + ca0.w;
      nv[4] = (v[4]-m)*inv*g1[c1+0] + b1g[c1+0] + ca1.x;
      nv[5] = (v[5]-m)*inv*g1[c1+1] + b1g[c1+1] + ca1.y;
      nv[6] = (v[6]-m)*inv*g1[c1+2] + b1g[c1+2] + ca1.z;
      nv[7] = (v[7]-m)*inv*g1[c1+3] + b1g[c1+3] + ca1.w;
      #pragma unroll
      for (int j = 0; j < 8; ++j){ u += nv[j]; u2 += nv[j]*nv[j]; }
      u = wave_sum(u); u2 = wave_sum(u2);
      float m2 = u*(1.f/EE), inv2 = rsqrtf(u2*(1.f/EE) - m2*m2 + 1e-5f);
      float o0 = (nv[0]-m2)*inv2*g2[c0+0] + b2g[c0+0];
      float o1 = (nv[1]-m2)*inv2*g2[c0+1] + b2g[c0+1];
      float o2v = (nv[2]-m2)*inv2*g2[c0+2] + b2g[c0+2];
      float o3 = (nv[3]-m2)*inv2*g2[c0+3] + b2g[c0+3];
      float o4 = (nv[4]-m2)*inv2*g2[c1+0] + b2g[c1+0];
      float o5 = (nv[5]-m2)*inv2*g2[c1+1] + b2g[c1+1];
      float o6 = (nv[6]-m2)*inv2*g2[c1+2] + b2g[c1+2];
      float o7 = (nv[7]-m2)*inv2*g2[c1+3] + b2g[c1+3];
      *(ull*)(xs + r*LDP + c0) = pkbf4(o0, o1, o2v, o3);
      *(ull*)(xs + r*LDP + c1) = pkbf4(o4, o5, o6, o7);
      if (yi){
        st_cv(yi + (size_t)r*EE + c0,     pk2(o0 + b2bias[c0+0], o1 + b2bias[c0+1]));
        st_cv(yi + (size_t)r*EE + c0 + 2, pk2(o2v + b2bias[c0+2], o3 + b2bias[c0+3]));
        st_cv(yi + (size_t)r*EE + c1,     pk2(o4 + b2bias[c1+0], o5 + b2bias[c1+1]));
        st_cv(yi + (size_t)r*EE + c1 + 2, pk2(o6 + b2bias[c1+2], o7 + b2bias[c1+3]));
      }
    }
    __syncthreads();
  }
  // ffn1 GEMM over block's 64 H-features
  {
    const int f0w = blk*64 + wv*16;
    const unsigned short* ar = w1b + (size_t)(f0w + lm)*EE + kg*8;
    f32x4 acc0 = {0.f,0.f,0.f,0.f}, acc1 = {0.f,0.f,0.f,0.f};
    #pragma unroll 4
    for (int ks = 0; ks < 16; ++ks){
      bf16x8 a  = *reinterpret_cast<const bf16x8*>(ar + ks*32);
      bf16x8 b0 = *reinterpret_cast<const bf16x8*>(b0r + ks*32);
      bf16x8 b1 = *reinterpret_cast<const bf16x8*>(b1r + ks*32);
      acc0 = mfma16(a, b0, acc0);
      acc1 = mfma16(a, b1, acc1);
    }
    const int fb = f0w + kg*4;
    float h0[4], h1[4];
    #pragma unroll
    for (int r = 0; r < 4; ++r){
      const float bv = b1bias[fb + r];
      float v0 = acc0[r] + bv, v1 = acc1[r] + bv;
      h0[r] = 0.5f*v0*(1.f + erff(v0*0.70710678118654752f));
      h1[r] = 0.5f*v1*(1.f + erff(v1*0.70710678118654752f));
    }
    st_cv(Hb + lm*FFD + fb,      pkbf4(h0[0], h0[1], h0[2], h0[3]));
    st_cv(Hb + (lm+16)*FFD + fb, pkbf4(h1[0], h1[1], h1[2], h1[3]));
  }
}

// C: ffn2 k-split, atomicAdd into yacc (base already written by B block0).
__device__ void ph_C(int blk, unsigned short* xs, const unsigned short* __restrict__ Hb,
    const unsigned short* __restrict__ w2b, float* __restrict__ yacc){
  const int t = threadIdx.x;
  const int k0 = (blk >> 3)*512;
  for (int i = t*16; i < BB*512; i += 4096){
    int r = i >> 9, c = i & 511;
    const unsigned short* s = Hb + (size_t)r*FFD + k0 + c;
    ull u0 = ld_cv(s), u1 = ld_cv(s+4), u2 = ld_cv(s+8), u3 = ld_cv(s+12);
    ull* dst = (ull*)(xs + r*LDP + c);
    dst[0] = u0; dst[1] = u1; dst[2] = u2; dst[3] = u3;
  }
  __syncthreads();
  const int wv = t >> 6, lane = t & 63;
  const int lm = lane & 15, kg = lane >> 4;
  const int f0w = (blk & 7)*64 + wv*16;
  const unsigned short* ar = w2b + (size_t)(f0w + lm)*FFD + k0 + kg*8;
  const unsigned short* b0r = xs + lm*LDP + kg*8;
  const unsigned short* b1r = xs + (lm+16)*LDP + kg*8;
  f32x4 acc0 = {0.f,0.f,0.f,0.f}, acc1 = {0.f,0.f,0.f,0.f};
  #pragma unroll 4
  for (int ks = 0; ks < 16; ++ks){
    bf16x8 a  = *reinterpret_cast<const bf16x8*>(ar + ks*32);
    bf16x8 b0 = *reinterpret_cast<const bf16x8*>(b0r + ks*32);
    bf16x8 b1 = *reinterpret_cast<const bf16x8*>(b1r + ks*32);
    acc0 = mfma16(a, b0, acc0);
    acc1 = mfma16(a, b1, acc1);
  }
  #pragma unroll
  for (int r = 0; r < 4; ++r){
    const int f = f0w + kg*4 + r;
    atomicAdd(&yacc[lm*EE + f], acc0[r]);      // device-scope, coherent
    atomicAdd(&yacc[(lm+16)*EE + f], acc1[r]);
  }
}

// LOG: LN3(yacc) -> logits slice (64 features per block, 128 blocks).
__device__ void ph_LOG(int blk, unsigned short* xs,
    const float* __restrict__ yacc, const float* __restrict__ lng, const float* __restrict__ lnb,
    const unsigned short* __restrict__ Wb, const float* __restrict__ bias,
    float* __restrict__ logits){
  stage_ln_reg(xs, yacc, lng, lnb, nullptr);
  const int t = threadIdx.x, wv = t >> 6, lane = t & 63;
  const int lm = lane & 15, kg = lane >> 4;
  const int f0w = blk*64 + wv*16;
  const unsigned short* ar = Wb + (size_t)(f0w + lm)*EE + kg*8;
  const unsigned short* b0r = xs + lm*LDP + kg*8;
  const unsigned short* b1r = xs + (lm+16)*LDP + kg*8;
  f32x4 acc0 = {0.f,0.f,0.f,0.f}, acc1 = {0.f,0.f,0.f,0.f};
  #pragma unroll 4
  for (int ks = 0; ks < 16; ++ks){
    bf16x8 a  = *reinterpret_cast<const bf16x8*>(ar + ks*32);
    bf16x8 b0 = *reinterpret_cast<const bf16x8*>(b0r + ks*32);
    bf16x8 b1 = *reinterpret_cast<const bf16x8*>(b1r + ks*32);
    acc0 = mfma16(a, b0, acc0);
    acc1 = mfma16(a, b1, acc1);
  }
  const int fb = f0w + kg*4;
  const float b0v = bias[fb], b1v = bias[fb+1], b2v = bias[fb+2], b3v = bias[fb+3];
  st_cv(logits + (size_t)lm*VV + fb,     pk2(acc0[0]+b0v, acc0[1]+b1v));
  st_cv(logits + (size_t)lm*VV + fb + 2, pk2(acc0[2]+b2v, acc0[3]+b3v));
  st_cv(logits + (size_t)(lm+16)*VV + fb,     pk2(acc1[0]+b0v, acc1[1]+b1v));
  st_cv(logits + (size_t)(lm+16)*VV + fb + 2, pk2(acc1[2]+b2v, acc1[3]+b3v));
}

// SM: dual softmax for batch row b; also zeroes x for embed accumulation.
__device__ void ph_SM(int b, float* red, const float* __restrict__ logits,
    const float* __restrict__ gum, float* __restrict__ dseq, float* __restrict__ ddist,
    unsigned short* __restrict__ sbf, float* __restrict__ x, int step){
  const int t = threadIdx.x, lane = t & 63, wv = t >> 6;
  const float* lr = logits + (size_t)b*VV;
  const float* gr = gum + (size_t)b*VV;
  float lv[32];
  #pragma unroll
  for (int g8 = 0; g8 < 8; ++g8){
    const int i0 = t*4 + g8*1024;
    upk2(ld_cv(lr + i0),     lv + g8*4);
    upk2(ld_cv(lr + i0 + 2), lv + g8*4 + 2);
  }
  float m1 = -1e30f, m2 = -1e30f;
  #pragma unroll
  for (int g8 = 0; g8 < 8; ++g8){
    const int i0 = t*4 + g8*1024;
    float4 gv = *(const float4*)(gr + i0);
    m1 = fmaxf(m1, fmaxf(fmaxf(lv[g8*4], lv[g8*4+1]), fmaxf(lv[g8*4+2], lv[g8*4+3])));
    m2 = fmaxf(m2, fmaxf(fmaxf(lv[g8*4]+gv.x, lv[g8*4+1]+gv.y),
                         fmaxf(lv[g8*4+2]+gv.z, lv[g8*4+3]+gv.w)));
  }
  for (int o = 32; o; o >>= 1){ m1 = fmaxf(m1, __shfl_down(m1,o)); m2 = fmaxf(m2, __shfl_down(m2,o)); }
  if (lane == 0){ red[wv] = m1; red[4+wv] = m2; }
  __syncthreads();
  m1 = fmaxf(fmaxf(red[0],red[1]), fmaxf(red[2],red[3]));
  m2 = fmaxf(fmaxf(red[4],red[5]), fmaxf(red[6],red[7]));
  __syncthreads();
  float s1 = 0.f, s2 = 0.f;
  #pragma unroll
  for (int g8 = 0; g8 < 8; ++g8){
    const int i0 = t*4 + g8*1024;
    float4 gv = *(const float4*)(gr + i0);
    s1 += __expf(lv[g8*4]-m1) + __expf(lv[g8*4+1]-m1) + __expf(lv[g8*4+2]-m1) + __expf(lv[g8*4+3]-m1);
    s2 += __expf(lv[g8*4]+gv.x-m2) + __expf(lv[g8*4+1]+gv.y-m2)
        + __expf(lv[g8*4+2]+gv.z-m2) + __expf(lv[g8*4+3]+gv.w-m2);
  }
  for (int o = 32; o; o >>= 1){ s1 += __shfl_down(s1,o); s2 += __shfl_down(s2,o); }
  if (lane == 0){ red[wv] = s1; red[4+wv] = s2; }
  __syncthreads();
  s1 = red[0]+red[1]+red[2]+red[3];
  s2 = red[4]+red[5]+red[6]+red[7];
  float r1 = 1.f/s1, r2 = 1.f/s2;
  float* dq = dseq + (size_t)b*((TT+1)*VV) + (size_t)step*VV;
  float* dd = ddist + (size_t)b*VV;
  #pragma unroll
  for (int g8 = 0; g8 < 8; ++g8){
    const int i0 = t*4 + g8*1024;
    float4 gv = *(const float4*)(gr + i0);
    float4 ddv, dqv;
    ddv.x = __expf(lv[g8*4]-m1)*r1;   ddv.y = __expf(lv[g8*4+1]-m1)*r1;
    ddv.z = __expf(lv[g8*4+2]-m1)*r1; ddv.w = __expf(lv[g8*4+3]-m1)*r1;
    dqv.x = __expf(lv[g8*4]+gv.x-m2)*r2;   dqv.y = __expf(lv[g8*4+1]+gv.y-m2)*r2;
    dqv.z = __expf(lv[g8*4+2]+gv.z-m2)*r2; dqv.w = __expf(lv[g8*4+3]+gv.w-m2)*r2;
    *(float4*)(dd + i0) = ddv;
    *(float4*)(dq + i0) = dqv;
    st_cv(sbf + (size_t)b*VV + i0, pkbf4(dqv.x, dqv.y, dqv.z, dqv.w));
  }
  st_cv(x + (size_t)b*EE + t*2, 0ull);
}

// EMB: x += (sample @ embT) * sqrt(E). 64 blocks = 8 e-tiles x 8 v-splits (K=1024).
__device__ void ph_EMB(int blk, unsigned short* rawbf, const unsigned short* __restrict__ eT,
    const unsigned short* __restrict__ sbf, float* __restrict__ x){
  const int t = threadIdx.x;
  const int et = blk & 7, v0 = (blk >> 3)*1024;
  for (int i = t*16; i < BB*1024; i += 4096){
    int r = i >> 10, c = i & 1023;
    const unsigned short* s = sbf + (size_t)r*VV + v0 + c;
    ull u0 = ld_cv(s), u1 = ld_cv(s+4), u2 = ld_cv(s+8), u3 = ld_cv(s+12);
    ull* dst = (ull*)(rawbf + r*EBP + c);
    dst[0] = u0; dst[1] = u1; dst[2] = u2; dst[3] = u3;
  }
  __syncthreads();
  const int wv = t >> 6, lane = t & 63;
  const int lm = lane & 15, kg = lane >> 4;
  const int e0w = et*64 + wv*16;
  const unsigned short* ar  = eT + (size_t)(e0w + lm)*VV + v0 + kg*8;
  const unsigned short* b0r = rawbf + lm*EBP + kg*8;
  const unsigned short* b1r = rawbf + (lm+16)*EBP + kg*8;
  f32x4 acc0 = {0.f,0.f,0.f,0.f}, acc1 = {0.f,0.f,0.f,0.f};
  #pragma unroll 8
  for (int ks = 0; ks < 32; ++ks){
    bf16x8 a  = *reinterpret_cast<const bf16x8*>(ar + ks*32);
    bf16x8 b0 = *reinterpret_cast<const bf16x8*>(b0r + ks*32);
    bf16x8 b1 = *reinterpret_cast<const bf16x8*>(b1r + ks*32);
    acc0 = mfma16(a, b0, acc0);
    acc1 = mfma16(a, b1, acc1);
  }
  #pragma unroll
  for (int r = 0; r < 4; ++r){
    const int e = e0w + kg*4 + r;
    atomicAdd(&x[lm*EE + e], acc0[r]*SCALE_EMB);
    atomicAdd(&x[(lm+16)*EE + e], acc1[r]*SCALE_EMB);
  }
}

// ---------------- the megakernel ----------------

struct MegaParams {
  float* x; float* xln; float* yacc0; float* yacc1; float* logits;
  const float* cac;
  float* kcache; float* vcache;
  unsigned short* obf; unsigned short* Hb; unsigned short* sbf;
  const unsigned short* wqkvb; const unsigned short* owb;
  const unsigned short* w1b; const unsigned short* w2b;
  const unsigned short* outwb; const unsigned short* eTb;
  const float* saqb; const float* saob;
  const float* l1g; const float* l1b; const float* l2g; const float* l2b;
  const float* l3g; const float* l3b;
  const float* b1; const float* b2; const float* outb; const float* gumb;
  float* dseq; float* ddist;
  unsigned* evt;
};

__global__ __launch_bounds__(256, 1) void k_mega(MegaParams P){
  __shared__ __align__(16) unsigned char SMEM[110080];
  unsigned short* xs = (unsigned short*)SMEM;                  // 33280 B  [32][520] bf16
  float* rawf        = (float*)(SMEM + 33280);                 // 66048 B  [32][516] f32
  unsigned short* rawbf = (unsigned short*)(SMEM + 33280);     //   (alias, [32][1032] bf16)
  float* qs  = (float*)(SMEM + 99328);                         //  8704 B  [32][68] f32
  float* att = (float*)(SMEM + 108032);                        //  2048 B
  const int blk = blockIdx.x;
  float* yp[2] = { P.yacc0, P.yacc1 };

  for (int step = 0; step < TT; ++step){
    const int tpos = step, tlen = step + 1;
    const int base = step*NPH_STEP;
    for (int l = 0; l < LL; ++l){
      const int use_ln = (l > 0);
      const int eA = base + l*3, eB = eA + 1, eC = eA + 2;
      float* ycur = yp[l & 1];
      const float* yprev = yp[(l-1) & 1];
      if (blk < NHD){
        // dep: l==0 -> EMB(step-1) [64]; else C(l-1) [32]
        if (l == 0){ if (step > 0) evt_wait(P.evt + (base - 1)*16, 64); }
        else         evt_wait(P.evt + (eA - 1)*16, 32);
        ph_A(blk, xs, qs, att, P.x, yprev,
             P.l3g + (use_ln ? (l-1)*EE : 0), P.l3b + (use_ln ? (l-1)*EE : 0), use_ln,
             P.wqkvb + (size_t)l*3*EE*EE, P.saqb + (size_t)l*3*EE,
             P.kcache + (size_t)l*BB*EE*TT, P.vcache + (size_t)l*BB*EE*TT,
             P.xln, P.obf, tpos, tlen);
        evt_post(P.evt + eA*16);
      }
      if (blk < 32){
        evt_wait(P.evt + eA*16, 8);
        ph_B(blk, xs, rawf, P.obf, use_ln ? P.xln : P.x,
             P.owb + (size_t)l*EE*EE, P.saob + (size_t)l*EE,
             P.cac + (size_t)l*BB*EE,
             P.l1g + l*EE, P.l1b + l*EE, P.l2g + l*EE, P.l2b + l*EE, P.b2 + l*EE,
             P.w1b + (size_t)l*FFD*EE, P.b1 + l*FFD, P.Hb, ycur);
        evt_post(P.evt + eB*16);
        evt_wait(P.evt + eB*16, 32);
        ph_C(blk, xs, P.Hb, P.w2b + (size_t)l*EE*FFD, ycur);
        evt_post(P.evt + eC*16);
      }
    }
    // LOG (all 128 blocks)
    evt_wait(P.evt + (base + 11)*16, 32);
    ph_LOG(blk, xs, yp[1], P.l3g + 3*EE, P.l3b + 3*EE, P.outwb, P.outb, P.logits);
    evt_post(P.evt + (base + 12)*16);
    // SM (32 blocks)
    if (blk < 32){
      evt_wait(P.evt + (base + 12)*16, 128);
      ph_SM(blk, att, P.logits, P.gumb + (size_t)step*BB*VV,
            P.dseq, P.ddist + (size_t)step*BB*VV, P.sbf, P.x, step);
      evt_post(P.evt + (base + 13)*16);
    }
    // EMB (64 blocks)
    if (blk < 64){
      evt_wait(P.evt + (base + 13)*16, 32);
      ph_EMB(blk, rawbf, P.eTb, P.sbf, P.x);
      evt_post(P.evt + (base + 14)*16);
    }
  }
}

// ---------------- host ----------------
extern "C" void kernel_launch(void* const* d_in, const int* in_sizes, int n_in,
                              void* d_out, int out_size, void* d_ws, size_t ws_size,
                              hipStream_t stream){
  (void)in_sizes; (void)n_in; (void)out_size; (void)ws_size;
  const float* enc  = (const float*)d_in[0];
  const float* spec = (const float*)d_in[1];
  const float* embw = (const float*)d_in[2];
  const float* outw = (const float*)d_in[3];
  const float* outb = (const float*)d_in[4];
  const float* gumb = (const float*)d_in[5];
  const float* saqw = (const float*)d_in[6];
  const float* saqb = (const float*)d_in[7];
  const float* saow = (const float*)d_in[8];
  const float* saob = (const float*)d_in[9];
  const float* caqw = (const float*)d_in[10];
  const float* caqb = (const float*)d_in[11];
  const float* caow = (const float*)d_in[12];
  const float* caob = (const float*)d_in[13];
  const float* l1g  = (const float*)d_in[14];
  const float* l1b  = (const float*)d_in[15];
  const float* l2g  = (const float*)d_in[16];
  const float* l2b  = (const float*)d_in[17];
  const float* l3g  = (const float*)d_in[18];
  const float* l3b  = (const float*)d_in[19];
  const float* w1   = (const float*)d_in[20];
  const float* b1   = (const float*)d_in[21];
  const float* w2   = (const float*)d_in[22];
  const float* b2   = (const float*)d_in[23];

  float* dout = (float*)d_out;
  float* dseq = dout;
  float* ddistbase = dout + (size_t)BB*(TT+1)*VV;

  unsigned char* p = (unsigned char*)d_ws;
  auto alloc = [&](size_t bytes) -> void* {
    void* r = (void*)p; p += (bytes + 255) & ~(size_t)255; return r;
  };
  float* x      = (float*)alloc(BB*EE*4);
  float* xln    = (float*)alloc(BB*EE*4);
  float* yacc0  = (float*)alloc(BB*EE*4);
  float* yacc1  = (float*)alloc(BB*EE*4);
  float* logits = (float*)alloc((size_t)BB*VV*4);
  float* venc   = (float*)alloc((size_t)LL*BB*EE*4);
  float* cac    = (float*)alloc((size_t)LL*BB*EE*4);
  float* kcache = (float*)alloc((size_t)LL*BB*EE*TT*4);
  float* vcache = (float*)alloc((size_t)LL*BB*EE*TT*4);
  unsigned short* obf   = (unsigned short*)alloc(BB*EE*2);
  unsigned short* Hb    = (unsigned short*)alloc(BB*FFD*2);
  unsigned short* sbf   = (unsigned short*)alloc((size_t)BB*VV*2);
  unsigned short* wqkvb = (unsigned short*)alloc((size_t)LL*3*EE*EE*2);
  unsigned short* owb   = (unsigned short*)alloc((size_t)LL*EE*EE*2);
  unsigned short* w1b   = (unsigned short*)alloc((size_t)LL*FFD*EE*2);
  unsigned short* w2b   = (unsigned short*)alloc((size_t)LL*FFD*EE*2);
  unsigned short* outwb = (unsigned short*)alloc((size_t)VV*EE*2);
  unsigned short* eTb   = (unsigned short*)alloc((size_t)EE*VV*2);
  unsigned* evt = (unsigned*)alloc(4096*4);

  // prologue: init (+event reset), cross-attn constants, bf16 weight conversions
  k_init<<<1104, 256, 0, stream>>>(spec, dseq, x, evt);
  k_penc<<<32, 256, 0, stream>>>(enc, caqw, caqb, venc);
  k_pca<<<32, 256, 0, stream>>>(venc, caow, caob, cac);
  k_cvt<<<(LL*3*EE*EE/4 + 255)/256, 256, 0, stream>>>(saqw, wqkvb, LL*3*EE*EE/4);
  k_cvt<<<(LL*EE*EE/4 + 255)/256, 256, 0, stream>>>(saow, owb, LL*EE*EE/4);
  k_cvt<<<(LL*FFD*EE/4 + 255)/256, 256, 0, stream>>>(w1, w1b, LL*FFD*EE/4);
  k_cvt<<<(LL*FFD*EE/4 + 255)/256, 256, 0, stream>>>(w2, w2b, LL*FFD*EE/4);
  k_cvt<<<(VV*EE/4 + 255)/256, 256, 0, stream>>>(outw, outwb, VV*EE/4);
  k_embT<<<1024, 256, 0, stream>>>(embw, eTb);

  MegaParams mp;
  mp.x = x; mp.xln = xln; mp.yacc0 = yacc0; mp.yacc1 = yacc1; mp.logits = logits;
  mp.cac = cac; mp.kcache = kcache; mp.vcache = vcache;
  mp.obf = obf; mp.Hb = Hb; mp.sbf = sbf;
  mp.wqkvb = wqkvb; mp.owb = owb; mp.w1b = w1b; mp.w2b = w2b;
  mp.outwb = outwb; mp.eTb = eTb;
  mp.saqb = saqb; mp.saob = saob;
  mp.l1g = l1g; mp.l1b = l1b; mp.l2g = l2g; mp.l2b = l2b;
  mp.l3g = l3g; mp.l3b = l3b;
  mp.b1 = b1; mp.b2 = b2; mp.outb = outb; mp.gumb = gumb;
  mp.dseq = dseq; mp.ddist = ddistbase;
  mp.evt = evt;

  // 128 persistent blocks, 110KB LDS -> 1 block/CU, all co-resident on 256 CUs.
  // Cross-block ordering via one-sided per-phase event counters (no grid barriers).
  k_mega<<<GRID_MEGA, 256, 0, stream>>>(mp);
}

// Round 5
// 5637.120 us; speedup vs baseline: 1.1977x; 1.1977x over previous
//
#include <hip/hip_runtime.h>
#include <math.h>

#define BB 32
#define EE 512
#define VV 8192
#define TT 16
#define LL 4
#define FFD 2048
#define NHD 8
#define HDD 64
#define LDP 520   // padded LDS pitch (bf16 elems)
#define RWP 516   // padded LDS pitch (f32 elems) for raw/o2 scratch
#define EBP 1032  // padded LDS pitch (bf16) for embed panel
#define OLP 72    // o_lds pitch (bf16): 144B rows, 16B-aligned
#define SCALE_EMB 22.627416997969522f
#define GRID_MEGA 128
#define NPH_STEP 15
#define EVS 256   // u32 stride between event slots (1 KB -> distinct IC lines)

typedef __attribute__((ext_vector_type(8))) short bf16x8;
typedef __attribute__((ext_vector_type(4))) float f32x4;
typedef unsigned long long ull;

__device__ __forceinline__ f32x4 mfma16(bf16x8 a, bf16x8 b, f32x4 c){
  return __builtin_amdgcn_mfma_f32_16x16x32_bf16(a, b, c, 0, 0, 0);
}

// ---------------- helpers ----------------
__device__ __forceinline__ float wave_sum(float v){
  for (int o = 32; o; o >>= 1) v += __shfl_down(v, o);
  return __shfl(v, 0);
}
__device__ __forceinline__ unsigned short f_to_bf(float f){
  unsigned u = __float_as_uint(f);
  unsigned r = (u + 0x7fffu + ((u >> 16) & 1u)) >> 16;
  return (unsigned short)r;
}
__device__ __forceinline__ float2 bf2_to_f2(const unsigned short* p){
  unsigned u = *(const unsigned*)p;
  float2 r;
  r.x = __uint_as_float(u << 16);
  r.y = __uint_as_float(u & 0xffff0000u);
  return r;
}

// coherent (cross-XCD) access primitives: bypass non-coherent per-XCD L2.
union UF { ull u; float f[2]; unsigned short s[4]; };
__device__ __forceinline__ ull ld_cv(const void* p){
  return __hip_atomic_load((const ull*)p, __ATOMIC_RELAXED, __HIP_MEMORY_SCOPE_AGENT);
}
__device__ __forceinline__ void st_cv(void* p, ull v){
  __hip_atomic_store((ull*)p, v, __ATOMIC_RELAXED, __HIP_MEMORY_SCOPE_AGENT);
}
__device__ __forceinline__ void upk2(ull u, float* f){ UF x; x.u = u; f[0] = x.f[0]; f[1] = x.f[1]; }
__device__ __forceinline__ ull pk2(float a, float b){ UF x; x.f[0] = a; x.f[1] = b; return x.u; }
__device__ __forceinline__ ull pkbf4(float a, float b, float c, float d){
  UF x; x.s[0] = f_to_bf(a); x.s[1] = f_to_bf(b); x.s[2] = f_to_bf(c); x.s[3] = f_to_bf(d); return x.u;
}

// ---- one-sided events: monotonic counter per phase instance (1 KB apart).
__device__ __forceinline__ void evt_post(unsigned* e){
  asm volatile("s_waitcnt vmcnt(0)" ::: "memory");
  __syncthreads();
  if (threadIdx.x == 0)
    __hip_atomic_fetch_add(e, 1u, __ATOMIC_RELAXED, __HIP_MEMORY_SCOPE_AGENT);
}
__device__ __forceinline__ void evt_wait(const unsigned* e, unsigned target){
  __syncthreads();
  if (threadIdx.x == 0){
    int it = 0;
    while (__hip_atomic_load(e, __ATOMIC_RELAXED, __HIP_MEMORY_SCOPE_AGENT) < target){
      // constant-arg backoff ladder (s_sleep requires a literal)
      if (it < 1)      __builtin_amdgcn_s_sleep(1);
      else if (it < 2) __builtin_amdgcn_s_sleep(2);
      else if (it < 4) __builtin_amdgcn_s_sleep(4);
      else if (it < 8) __builtin_amdgcn_s_sleep(8);
      else             __builtin_amdgcn_s_sleep(16);
      ++it;
    }
  }
  __syncthreads();
  asm volatile("" ::: "memory");
}

// fp32 VALU GEMM core (kept for the one-off prologue kernels k_penc/k_pca)
__device__ __forceinline__ void gemm_chunk(const float* __restrict__ wrow0, int ldw,
    const unsigned short* xs, float* wt, float acc[4][2]){
  const int t = threadIdx.x, fg = t & 15, bg = t >> 4;
  #pragma unroll 1
  for (int c = 0; c < 8; ++c){
    const int k0 = c*64;
    __syncthreads();
    {
      int i = t*4;
      #pragma unroll
      for (int p = 0; p < 4; ++p, i += 1024){
        const int fr = i >> 6, kk = i & 63;
        float4 v = *(const float4*)(wrow0 + (size_t)fr*ldw + k0 + kk);
        wt[(kk+0)*68 + fr] = v.x;
        wt[(kk+1)*68 + fr] = v.y;
        wt[(kk+2)*68 + fr] = v.z;
        wt[(kk+3)*68 + fr] = v.w;
      }
    }
    __syncthreads();
    const unsigned short* xr0 = xs + (bg*2)*EE + k0;
    const unsigned short* xr1 = xr0 + EE;
    #pragma unroll 8
    for (int k = 0; k < 64; k += 2){
      float w0[4], w1[4];
      *(float4*)w0 = *(const float4*)(wt + (k+0)*68 + fg*4);
      *(float4*)w1 = *(const float4*)(wt + (k+1)*68 + fg*4);
      float2 xv0 = bf2_to_f2(xr0 + k);
      float2 xv1 = bf2_to_f2(xr1 + k);
      #pragma unroll
      for (int i = 0; i < 4; ++i){
        acc[i][0] += w0[i]*xv0.x + w1[i]*xv0.y;
        acc[i][1] += w0[i]*xv1.x + w1[i]*xv1.y;
      }
    }
  }
}

// Stage raw [B,E] f32 -> LDS bf16 (no LN), coherent loads.
__device__ __forceinline__ void stage_plain(unsigned short* xs, const float* __restrict__ xsrc){
  #pragma unroll 4
  for (int i = threadIdx.x*4; i < BB*EE; i += 1024){
    ull u0 = ld_cv(xsrc + i);
    ull u1 = ld_cv(xsrc + i + 2);
    int r = i >> 9, c = i & 511;
    float f0[2], f1[2]; upk2(u0, f0); upk2(u1, f1);
    *(ull*)(xs + r*LDP + c) = pkbf4(f0[0], f0[1], f1[0], f1[1]);
  }
  __syncthreads();
}

// Stage [B,E] with pending LN: all 32 coherent loads issued upfront (registers),
// then per-row LN -> LDS bf16; optional LN'd f32 rows to xlnout (coherent).
__device__ __forceinline__ void stage_ln_reg(unsigned short* xs, const float* __restrict__ ybuf,
    const float* __restrict__ g, const float* __restrict__ bt, float* __restrict__ xlnout){
  const int lane = threadIdx.x & 63, wv = threadIdx.x >> 6;
  const int c0 = lane*4, c1 = 256 + lane*4;
  float ga[8], ba[8];
  #pragma unroll
  for (int k = 0; k < 4; ++k){ ga[k] = g[c0+k]; ga[4+k] = g[c1+k]; ba[k] = bt[c0+k]; ba[4+k] = bt[c1+k]; }
  ull a[8][4];
  #pragma unroll
  for (int j = 0; j < 8; ++j){
    const float* yr = ybuf + (size_t)(wv*8+j)*EE;
    a[j][0] = ld_cv(yr + c0); a[j][1] = ld_cv(yr + c0 + 2);
    a[j][2] = ld_cv(yr + c1); a[j][3] = ld_cv(yr + c1 + 2);
  }
  #pragma unroll
  for (int j = 0; j < 8; ++j){
    const int r = wv*8 + j;
    float v[8];
    upk2(a[j][0], v+0); upk2(a[j][1], v+2); upk2(a[j][2], v+4); upk2(a[j][3], v+6);
    float s = 0.f, s2 = 0.f;
    #pragma unroll
    for (int k = 0; k < 8; ++k){ s += v[k]; s2 += v[k]*v[k]; }
    s = wave_sum(s); s2 = wave_sum(s2);
    float m = s * (1.f/EE);
    float inv = rsqrtf(s2*(1.f/EE) - m*m + 1e-5f);
    float o_[8];
    #pragma unroll
    for (int k = 0; k < 8; ++k) o_[k] = (v[k]-m)*inv*ga[k] + ba[k];
    *(ull*)(xs + r*LDP + c0) = pkbf4(o_[0], o_[1], o_[2], o_[3]);
    *(ull*)(xs + r*LDP + c1) = pkbf4(o_[4], o_[5], o_[6], o_[7]);
    if (xlnout){
      st_cv(xlnout + (size_t)r*EE + c0,     pk2(o_[0], o_[1]));
      st_cv(xlnout + (size_t)r*EE + c0 + 2, pk2(o_[2], o_[3]));
      st_cv(xlnout + (size_t)r*EE + c1,     pk2(o_[4], o_[5]));
      st_cv(xlnout + (size_t)r*EE + c1 + 2, pk2(o_[6], o_[7]));
    }
  }
  __syncthreads();
}

// ---------------- prologue kernels ----------------

__global__ __launch_bounds__(256) void k_init(const float* __restrict__ special,
    float* __restrict__ dseq, float* __restrict__ x,
    float* __restrict__ o2a, float* __restrict__ o2b, unsigned* __restrict__ evt){
  int idx = blockIdx.x*256 + threadIdx.x;
  if (idx < BB*VV){
    int b = idx >> 13, v = idx & (VV-1);
    dseq[(size_t)b*((TT+1)*VV) + (size_t)TT*VV + v] = (v == 0) ? 1.f : 0.f;
  } else if (idx < BB*VV + BB*EE){
    int i = idx - BB*VV;
    x[i] = special[i & (EE-1)];
  } else if (idx < BB*VV + 2*BB*EE){
    o2a[idx - BB*VV - BB*EE] = 0.f;
  } else if (idx < BB*VV + 3*BB*EE){
    o2b[idx - BB*VV - 2*BB*EE] = 0.f;
  } else {
    int i = idx - BB*VV - 3*BB*EE;
    if (i < NPH_STEP*TT*EVS) evt[i] = 0u;
  }
}

__global__ __launch_bounds__(256) void k_penc(const float* __restrict__ enc,
    const float* __restrict__ w, const float* __restrict__ bias, float* __restrict__ venc){
  __shared__ unsigned short xs[BB*EE];
  __shared__ float wt[64*68];
  const int l = blockIdx.x >> 3, et = blockIdx.x & 7;
  for (int i = threadIdx.x; i < BB*EE; i += 256) xs[i] = f_to_bf(enc[i]);
  const int t = threadIdx.x, fg = t & 15, bg = t >> 4;
  const int f0 = et*64;
  const float* wl = w + (size_t)l*3*EE*EE + (size_t)(2*EE + f0)*EE;
  const float* bl = bias + l*3*EE + 2*EE + f0;
  float acc[4][2];
  #pragma unroll
  for (int i = 0; i < 4; ++i){ float bv = bl[fg*4+i]; acc[i][0] = bv; acc[i][1] = bv; }
  gemm_chunk(wl, EE, xs, wt, acc);
  #pragma unroll
  for (int i = 0; i < 4; ++i)
    #pragma unroll
    for (int j = 0; j < 2; ++j)
      venc[(size_t)l*BB*EE + (bg*2+j)*EE + f0 + fg*4 + i] = acc[i][j];
}

__global__ __launch_bounds__(256) void k_pca(const float* __restrict__ venc,
    const float* __restrict__ w, const float* __restrict__ bias, float* __restrict__ cac){
  __shared__ unsigned short xs[BB*EE];
  __shared__ float wt[64*68];
  const int l = blockIdx.x >> 3, et = blockIdx.x & 7;
  const float* vin = venc + (size_t)l*BB*EE;
  for (int i = threadIdx.x; i < BB*EE; i += 256) xs[i] = f_to_bf(vin[i]);
  const int t = threadIdx.x, fg = t & 15, bg = t >> 4;
  const int f0 = et*64;
  const float* wl = w + (size_t)l*EE*EE + (size_t)f0*EE;
  const float* bl = bias + l*EE + f0;
  float acc[4][2];
  #pragma unroll
  for (int i = 0; i < 4; ++i){ float bv = bl[fg*4+i]; acc[i][0] = bv; acc[i][1] = bv; }
  gemm_chunk(wl, EE, xs, wt, acc);
  #pragma unroll
  for (int i = 0; i < 4; ++i)
    #pragma unroll
    for (int j = 0; j < 2; ++j)
      cac[(size_t)l*BB*EE + (bg*2+j)*EE + f0 + fg*4 + i] = acc[i][j];
}

__global__ __launch_bounds__(256) void k_cvt(const float* __restrict__ s,
    unsigned short* __restrict__ d, int n4){
  int i = blockIdx.x*256 + threadIdx.x;
  if (i < n4){
    float4 v = ((const float4*)s)[i];
    ushort4 o;
    o.x = f_to_bf(v.x); o.y = f_to_bf(v.y); o.z = f_to_bf(v.z); o.w = f_to_bf(v.w);
    ((ushort4*)d)[i] = o;
  }
}

__global__ __launch_bounds__(256) void k_embT(const float* __restrict__ emb,
    unsigned short* __restrict__ eT){
  __shared__ unsigned short tl[64][68];
  const int vt = blockIdx.x >> 3, et = blockIdx.x & 7;
  const int v0 = vt*64, e0 = et*64;
  for (int i = threadIdx.x; i < 64*64; i += 256){
    int vv = i >> 6, ee = i & 63;
    tl[vv][ee] = f_to_bf(emb[(size_t)(v0+vv)*EE + e0 + ee]);
  }
  __syncthreads();
  for (int i = threadIdx.x; i < 64*64; i += 256){
    int ee = i >> 6, vv = i & 63;
    eT[(size_t)(e0+ee)*VV + v0 + vv] = tl[vv][ee];
  }
}

// ---------------- mega-kernel phases ----------------

// A: qkv + attention + out-projection k-split (head h slice of W_out) -> atomicAdd o2.
__device__ void ph_A(int h, unsigned short* xs, float* qs, float* att,
    const float* __restrict__ xsrc, const float* __restrict__ yprev,
    const float* __restrict__ lg, const float* __restrict__ lb, int use_ln,
    const unsigned short* __restrict__ Wb, const float* __restrict__ bias,
    const unsigned short* __restrict__ owb_l,
    float* __restrict__ kcl, float* __restrict__ vcl, float* __restrict__ xln,
    float* __restrict__ o2acc, int tpos, int tlen){
  if (use_ln) stage_ln_reg(xs, yprev, lg, lb, (h == 0) ? xln : nullptr);
  else        stage_plain(xs, xsrc);
  const int t = threadIdx.x, wv = t >> 6, lane = t & 63;
  const int lm = lane & 15, kg = lane >> 4;
  const unsigned short* b0r = xs + lm*LDP + kg*8;
  const unsigned short* b1r = xs + (lm+16)*LDP + kg*8;
  #pragma unroll
  for (int c = 0; c < 3; ++c){
    const int fbase = c*EE + h*64 + wv*16;
    const unsigned short* ar = Wb + (size_t)(fbase + lm)*EE + kg*8;
    f32x4 acc0 = {0.f,0.f,0.f,0.f}, acc1 = {0.f,0.f,0.f,0.f};
    #pragma unroll 4
    for (int ks = 0; ks < 16; ++ks){
      bf16x8 a  = *reinterpret_cast<const bf16x8*>(ar + ks*32);
      bf16x8 b0 = *reinterpret_cast<const bf16x8*>(b0r + ks*32);
      bf16x8 b1 = *reinterpret_cast<const bf16x8*>(b1r + ks*32);
      acc0 = mfma16(a, b0, acc0);
      acc1 = mfma16(a, b1, acc1);
    }
    #pragma unroll
    for (int r = 0; r < 4; ++r){
      const int frel = wv*16 + kg*4 + r;
      const float bv = bias[c*EE + h*64 + frel];
      float v0 = acc0[r] + bv, v1 = acc1[r] + bv;
      if (c == 0){
        qs[lm*68 + frel] = v0;
        qs[(lm+16)*68 + frel] = v1;
      } else if (c == 1){
        kcl[((lm*NHD + h)*TT + tpos)*HDD + frel] = v0;       // block-private
        kcl[(((lm+16)*NHD + h)*TT + tpos)*HDD + frel] = v1;
      } else {
        vcl[((lm*NHD + h)*TT + tpos)*HDD + frel] = v0;
        vcl[(((lm+16)*NHD + h)*TT + tpos)*HDD + frel] = v1;
      }
    }
  }
  __syncthreads();
  // scores
  #pragma unroll
  for (int pp = 0; pp < 2; ++pp){
    const int p = t + pp*256;
    const int b = p >> 4, j = p & 15;
    if (j < tlen){
      const float* qrow = qs + b*68;
      const float* krow = kcl + ((b*NHD + h)*TT + j)*HDD;
      float a = 0.f;
      #pragma unroll
      for (int d = 0; d < HDD; d += 4){
        float4 qv = *(const float4*)(qrow + d);
        float4 kv = *(const float4*)(krow + d);
        a += qv.x*kv.x + qv.y*kv.y + qv.z*kv.z + qv.w*kv.w;
      }
      att[b*16 + j] = a*0.125f;
    }
  }
  __syncthreads();
  if (t < 32){
    const int b = t;
    float m = -1e30f;
    for (int j = 0; j < tlen; ++j) m = fmaxf(m, att[b*16 + j]);
    float s = 0.f;
    for (int j = 0; j < tlen; ++j) s += __expf(att[b*16 + j] - m);
    float inv = 1.f/s;
    for (int j = 0; j < tlen; ++j) att[b*16 + j] = __expf(att[b*16 + j] - m)*inv;
  }
  __syncthreads();
  // PV -> o_lds (bf16, pitch OLP); reuses qs area (qs reads all done)
  unsigned short* o_lds = (unsigned short*)qs;
  {
    const int b = t >> 3, d0 = (t & 7)*8;
    float acc[8];
    #pragma unroll
    for (int i = 0; i < 8; ++i) acc[i] = 0.f;
    const float* vrow = vcl + ((b*NHD + h)*TT)*HDD + d0;
    for (int j = 0; j < tlen; ++j){
      const float a = att[b*16 + j];
      float4 v0 = *(const float4*)(vrow + j*HDD);
      float4 v1 = *(const float4*)(vrow + j*HDD + 4);
      acc[0] += a*v0.x; acc[1] += a*v0.y; acc[2] += a*v0.z; acc[3] += a*v0.w;
      acc[4] += a*v1.x; acc[5] += a*v1.y; acc[6] += a*v1.z; acc[7] += a*v1.w;
    }
    *(ull*)(o_lds + b*OLP + d0)     = pkbf4(acc[0], acc[1], acc[2], acc[3]);
    *(ull*)(o_lds + b*OLP + d0 + 4) = pkbf4(acc[4], acc[5], acc[6], acc[7]);
  }
  __syncthreads();
  // out-projection partial: o_h[32,64] x Wout[:, h*64:h*64+64]^T -> atomicAdd o2
  const unsigned short* ob0 = o_lds + lm*OLP + kg*8;
  const unsigned short* ob1 = o_lds + (lm+16)*OLP + kg*8;
  #pragma unroll
  for (int ft = 0; ft < 8; ++ft){
    const int f0 = wv*128 + ft*16;
    const unsigned short* ar = owb_l + (size_t)(f0 + lm)*EE + h*HDD + kg*8;
    f32x4 a0 = {0.f,0.f,0.f,0.f}, a1 = {0.f,0.f,0.f,0.f};
    #pragma unroll
    for (int ks = 0; ks < 2; ++ks){
      bf16x8 a  = *reinterpret_cast<const bf16x8*>(ar + ks*32);
      bf16x8 x0 = *reinterpret_cast<const bf16x8*>(ob0 + ks*32);
      bf16x8 x1 = *reinterpret_cast<const bf16x8*>(ob1 + ks*32);
      a0 = mfma16(a, x0, a0);
      a1 = mfma16(a, x1, a1);
    }
    #pragma unroll
    for (int r = 0; r < 4; ++r){
      const int f = f0 + kg*4 + r;
      atomicAdd(&o2acc[lm*EE + f], a0[r]);
      atomicAdd(&o2acc[(lm+16)*EE + f], a1[r]);
    }
  }
}

// B: stage (o2 + resid + ob) -> LDS f32, LN1(+cac) -> LN2 -> ffn1 GEMM (64 H-feats).
// blk0 also writes yacc base = LN2out + b2bias.
__device__ void ph_B(int blk, unsigned short* xs, float* rawf,
    const float* __restrict__ o2buf, const float* __restrict__ resid,
    const float* __restrict__ ob, const float* __restrict__ cac,
    const float* __restrict__ g1, const float* __restrict__ b1g,
    const float* __restrict__ g2, const float* __restrict__ b2g,
    const float* __restrict__ b2bias,
    const unsigned short* __restrict__ w1b, const float* __restrict__ b1bias,
    unsigned short* __restrict__ Hb, float* __restrict__ yacc){
  const int t = threadIdx.x;
  #pragma unroll 4
  for (int i = t*4; i < BB*EE; i += 1024){
    const int r = i >> 9, c = i & 511;
    ull a0 = ld_cv(o2buf + i), a1 = ld_cv(o2buf + i + 2);
    ull r0 = ld_cv(resid + i), r1 = ld_cv(resid + i + 2);
    float4 obv = *(const float4*)(ob + c);
    float fa[2], fb[2], fr0[2], fr1[2];
    upk2(a0, fa); upk2(a1, fb); upk2(r0, fr0); upk2(r1, fr1);
    rawf[r*RWP + c]     = fa[0] + fr0[0] + obv.x;
    rawf[r*RWP + c + 1] = fa[1] + fr0[1] + obv.y;
    rawf[r*RWP + c + 2] = fb[0] + fr1[0] + obv.z;
    rawf[r*RWP + c + 3] = fb[1] + fr1[1] + obv.w;
  }
  __syncthreads();
  const int wv = t >> 6, lane = t & 63;
  const int lm = lane & 15, kg = lane >> 4;
  // LN1 (+cac) -> LN2 -> xs bf16; blk0 writes yacc base = LN2out + b2bias
  {
    float* yi = (blk == 0) ? yacc : nullptr;
    const int c0 = lane*4, c1 = 256 + lane*4;
    for (int r = wv*8; r < wv*8 + 8; ++r){
      float v[8];
      *(float4*)(v+0) = *(const float4*)(rawf + r*RWP + c0);
      *(float4*)(v+4) = *(const float4*)(rawf + r*RWP + c1);
      float s = 0.f, s2 = 0.f;
      #pragma unroll
      for (int j = 0; j < 8; ++j){ s += v[j]; s2 += v[j]*v[j]; }
      s = wave_sum(s); s2 = wave_sum(s2);
      float m = s*(1.f/EE), inv = rsqrtf(s2*(1.f/EE) - m*m + 1e-5f);
      float4 ca0 = *(const float4*)(cac + (size_t)r*EE + c0);
      float4 ca1 = *(const float4*)(cac + (size_t)r*EE + c1);
      float nv[8]; float u = 0.f, u2 = 0.f;
      nv[0] = (v[0]-m)*inv*g1[c0+0] + b1g[c0+0] + ca0.x;
      nv[1] = (v[1]-m)*inv*g1[c0+1] + b1g[c0+1] + ca0.y;
      nv[2] = (v[2]-m)*inv*g1[c0+2] + b1g[c0+2] + ca0.z;
      nv[3] = (v[3]-m)*inv*g1[c0+3] + b1g[c0+3] + ca0.w;
      nv[4] = (v[4]-m)*inv*g1[c1+0] + b1g[c1+0] + ca1.x;
      nv[5] = (v[5]-m)*inv*g1[c1+1] + b1g[c1+1] + ca1.y;
      nv[6] = (v[6]-m)*inv*g1[c1+2] + b1g[c1+2] + ca1.z;
      nv[7] = (v[7]-m)*inv*g1[c1+3] + b1g[c1+3] + ca1.w;
      #pragma unroll
      for (int j = 0; j < 8; ++j){ u += nv[j]; u2 += nv[j]*nv[j]; }
      u = wave_sum(u); u2 = wave_sum(u2);
      float m2 = u*(1.f/EE), inv2 = rsqrtf(u2*(1.f/EE) - m2*m2 + 1e-5f);
      float o0 = (nv[0]-m2)*inv2*g2[c0+0] + b2g[c0+0];
      float o1 = (nv[1]-m2)*inv2*g2[c0+1] + b2g[c0+1];
      float o2v = (nv[2]-m2)*inv2*g2[c0+2] + b2g[c0+2];
      float o3 = (nv[3]-m2)*inv2*g2[c0+3] + b2g[c0+3];
      float o4 = (nv[4]-m2)*inv2*g2[c1+0] + b2g[c1+0];
      float o5 = (nv[5]-m2)*inv2*g2[c1+1] + b2g[c1+1];
      float o6 = (nv[6]-m2)*inv2*g2[c1+2] + b2g[c1+2];
      float o7 = (nv[7]-m2)*inv2*g2[c1+3] + b2g[c1+3];
      *(ull*)(xs + r*LDP + c0) = pkbf4(o0, o1, o2v, o3);
      *(ull*)(xs + r*LDP + c1) = pkbf4(o4, o5, o6, o7);
      if (yi){
        st_cv(yi + (size_t)r*EE + c0,     pk2(o0 + b2bias[c0+0], o1 + b2bias[c0+1]));
        st_cv(yi + (size_t)r*EE + c0 + 2, pk2(o2v + b2bias[c0+2], o3 + b2bias[c0+3]));
        st_cv(yi + (size_t)r*EE + c1,     pk2(o4 + b2bias[c1+0], o5 + b2bias[c1+1]));
        st_cv(yi + (size_t)r*EE + c1 + 2, pk2(o6 + b2bias[c1+2], o7 + b2bias[c1+3]));
      }
    }
    __syncthreads();
  }
  // ffn1 GEMM over block's 64 H-features
  {
    const int f0w = blk*64 + wv*16;
    const unsigned short* ar = w1b + (size_t)(f0w + lm)*EE + kg*8;
    const unsigned short* b0r = xs + lm*LDP + kg*8;
    const unsigned short* b1r = xs + (lm+16)*LDP + kg*8;
    f32x4 acc0 = {0.f,0.f,0.f,0.f}, acc1 = {0.f,0.f,0.f,0.f};
    #pragma unroll 4
    for (int ks = 0; ks < 16; ++ks){
      bf16x8 a  = *reinterpret_cast<const bf16x8*>(ar + ks*32);
      bf16x8 b0 = *reinterpret_cast<const bf16x8*>(b0r + ks*32);
      bf16x8 b1 = *reinterpret_cast<const bf16x8*>(b1r + ks*32);
      acc0 = mfma16(a, b0, acc0);
      acc1 = mfma16(a, b1, acc1);
    }
    const int fb = f0w + kg*4;
    float h0[4], h1[4];
    #pragma unroll
    for (int r = 0; r < 4; ++r){
      const float bv = b1bias[fb + r];
      float v0 = acc0[r] + bv, v1 = acc1[r] + bv;
      h0[r] = 0.5f*v0*(1.f + erff(v0*0.70710678118654752f));
      h1[r] = 0.5f*v1*(1.f + erff(v1*0.70710678118654752f));
    }
    st_cv(Hb + lm*FFD + fb,      pkbf4(h0[0], h0[1], h0[2], h0[3]));
    st_cv(Hb + (lm+16)*FFD + fb, pkbf4(h1[0], h1[1], h1[2], h1[3]));
  }
}

// C: ffn2 k-split, atomicAdd into yacc; then zero this block's slice of o2 (WAR-safe:
// all B blocks finished staging o2 before C starts).
__device__ void ph_C(int blk, unsigned short* xs, const unsigned short* __restrict__ Hb,
    const unsigned short* __restrict__ w2b, float* __restrict__ yacc,
    float* __restrict__ o2zero){
  const int t = threadIdx.x;
  const int k0 = (blk >> 3)*512;
  for (int i = t*16; i < BB*512; i += 4096){
    int r = i >> 9, c = i & 511;
    const unsigned short* s = Hb + (size_t)r*FFD + k0 + c;
    ull u0 = ld_cv(s), u1 = ld_cv(s+4), u2 = ld_cv(s+8), u3 = ld_cv(s+12);
    ull* dst = (ull*)(xs + r*LDP + c);
    dst[0] = u0; dst[1] = u1; dst[2] = u2; dst[3] = u3;
  }
  __syncthreads();
  const int wv = t >> 6, lane = t & 63;
  const int lm = lane & 15, kg = lane >> 4;
  const int f0w = (blk & 7)*64 + wv*16;
  const unsigned short* ar = w2b + (size_t)(f0w + lm)*FFD + k0 + kg*8;
  const unsigned short* b0r = xs + lm*LDP + kg*8;
  const unsigned short* b1r = xs + (lm+16)*LDP + kg*8;
  f32x4 acc0 = {0.f,0.f,0.f,0.f}, acc1 = {0.f,0.f,0.f,0.f};
  #pragma unroll 4
  for (int ks = 0; ks < 16; ++ks){
    bf16x8 a  = *reinterpret_cast<const bf16x8*>(ar + ks*32);
    bf16x8 b0 = *reinterpret_cast<const bf16x8*>(b0r + ks*32);
    bf16x8 b1 = *reinterpret_cast<const bf16x8*>(b1r + ks*32);
    acc0 = mfma16(a, b0, acc0);
    acc1 = mfma16(a, b1, acc1);
  }
  #pragma unroll
  for (int r = 0; r < 4; ++r){
    const int f = f0w + kg*4 + r;
    atomicAdd(&yacc[lm*EE + f], acc0[r]);
    atomicAdd(&yacc[(lm+16)*EE + f], acc1[r]);
  }
  st_cv(o2zero + blk*512 + t*2, 0ull);
}

// LOG: LN3(yacc) -> logits slice (64 features per block, 128 blocks).
__device__ void ph_LOG(int blk, unsigned short* xs,
    const float* __restrict__ yacc, const float* __restrict__ lng, const float* __restrict__ lnb,
    const unsigned short* __restrict__ Wb, const float* __restrict__ bias,
    float* __restrict__ logits){
  stage_ln_reg(xs, yacc, lng, lnb, nullptr);
  const int t = threadIdx.x, wv = t >> 6, lane = t & 63;
  const int lm = lane & 15, kg = lane >> 4;
  const int f0w = blk*64 + wv*16;
  const unsigned short* ar = Wb + (size_t)(f0w + lm)*EE + kg*8;
  const unsigned short* b0r = xs + lm*LDP + kg*8;
  const unsigned short* b1r = xs + (lm+16)*LDP + kg*8;
  f32x4 acc0 = {0.f,0.f,0.f,0.f}, acc1 = {0.f,0.f,0.f,0.f};
  #pragma unroll 4
  for (int ks = 0; ks < 16; ++ks){
    bf16x8 a  = *reinterpret_cast<const bf16x8*>(ar + ks*32);
    bf16x8 b0 = *reinterpret_cast<const bf16x8*>(b0r + ks*32);
    bf16x8 b1 = *reinterpret_cast<const bf16x8*>(b1r + ks*32);
    acc0 = mfma16(a, b0, acc0);
    acc1 = mfma16(a, b1, acc1);
  }
  const int fb = f0w + kg*4;
  const float b0v = bias[fb], b1v = bias[fb+1], b2v = bias[fb+2], b3v = bias[fb+3];
  st_cv(logits + (size_t)lm*VV + fb,     pk2(acc0[0]+b0v, acc0[1]+b1v));
  st_cv(logits + (size_t)lm*VV + fb + 2, pk2(acc0[2]+b2v, acc0[3]+b3v));
  st_cv(logits + (size_t)(lm+16)*VV + fb,     pk2(acc1[0]+b0v, acc1[1]+b1v));
  st_cv(logits + (size_t)(lm+16)*VV + fb + 2, pk2(acc1[2]+b2v, acc1[3]+b3v));
}

// SM: dual softmax for batch row b; also zeroes x for embed accumulation.
__device__ void ph_SM(int b, float* red, const float* __restrict__ logits,
    const float* __restrict__ gum, float* __restrict__ dseq, float* __restrict__ ddist,
    unsigned short* __restrict__ sbf, float* __restrict__ x, int step){
  const int t = threadIdx.x, lane = t & 63, wv = t >> 6;
  const float* lr = logits + (size_t)b*VV;
  const float* gr = gum + (size_t)b*VV;
  float lv[32];
  #pragma unroll
  for (int g8 = 0; g8 < 8; ++g8){
    const int i0 = t*4 + g8*1024;
    upk2(ld_cv(lr + i0),     lv + g8*4);
    upk2(ld_cv(lr + i0 + 2), lv + g8*4 + 2);
  }
  float m1 = -1e30f, m2 = -1e30f;
  #pragma unroll
  for (int g8 = 0; g8 < 8; ++g8){
    const int i0 = t*4 + g8*1024;
    float4 gv = *(const float4*)(gr + i0);
    m1 = fmaxf(m1, fmaxf(fmaxf(lv[g8*4], lv[g8*4+1]), fmaxf(lv[g8*4+2], lv[g8*4+3])));
    m2 = fmaxf(m2, fmaxf(fmaxf(lv[g8*4]+gv.x, lv[g8*4+1]+gv.y),
                         fmaxf(lv[g8*4+2]+gv.z, lv[g8*4+3]+gv.w)));
  }
  for (int o = 32; o; o >>= 1){ m1 = fmaxf(m1, __shfl_down(m1,o)); m2 = fmaxf(m2, __shfl_down(m2,o)); }
  if (lane == 0){ red[wv] = m1; red[4+wv] = m2; }
  __syncthreads();
  m1 = fmaxf(fmaxf(red[0],red[1]), fmaxf(red[2],red[3]));
  m2 = fmaxf(fmaxf(red[4],red[5]), fmaxf(red[6],red[7]));
  __syncthreads();
  float s1 = 0.f, s2 = 0.f;
  #pragma unroll
  for (int g8 = 0; g8 < 8; ++g8){
    const int i0 = t*4 + g8*1024;
    float4 gv = *(const float4*)(gr + i0);
    s1 += __expf(lv[g8*4]-m1) + __expf(lv[g8*4+1]-m1) + __expf(lv[g8*4+2]-m1) + __expf(lv[g8*4+3]-m1);
    s2 += __expf(lv[g8*4]+gv.x-m2) + __expf(lv[g8*4+1]+gv.y-m2)
        + __expf(lv[g8*4+2]+gv.z-m2) + __expf(lv[g8*4+3]+gv.w-m2);
  }
  for (int o = 32; o; o >>= 1){ s1 += __shfl_down(s1,o); s2 += __shfl_down(s2,o); }
  if (lane == 0){ red[wv] = s1; red[4+wv] = s2; }
  __syncthreads();
  s1 = red[0]+red[1]+red[2]+red[3];
  s2 = red[4]+red[5]+red[6]+red[7];
  float r1 = 1.f/s1, r2 = 1.f/s2;
  float* dq = dseq + (size_t)b*((TT+1)*VV) + (size_t)step*VV;
  float* dd = ddist + (size_t)b*VV;
  #pragma unroll
  for (int g8 = 0; g8 < 8; ++g8){
    const int i0 = t*4 + g8*1024;
    float4 gv = *(const float4*)(gr + i0);
    float4 ddv, dqv;
    ddv.x = __expf(lv[g8*4]-m1)*r1;   ddv.y = __expf(lv[g8*4+1]-m1)*r1;
    ddv.z = __expf(lv[g8*4+2]-m1)*r1; ddv.w = __expf(lv[g8*4+3]-m1)*r1;
    dqv.x = __expf(lv[g8*4]+gv.x-m2)*r2;   dqv.y = __expf(lv[g8*4+1]+gv.y-m2)*r2;
    dqv.z = __expf(lv[g8*4+2]+gv.z-m2)*r2; dqv.w = __expf(lv[g8*4+3]+gv.w-m2)*r2;
    *(float4*)(dd + i0) = ddv;
    *(float4*)(dq + i0) = dqv;
    st_cv(sbf + (size_t)b*VV + i0, pkbf4(dqv.x, dqv.y, dqv.z, dqv.w));
  }
  st_cv(x + (size_t)b*EE + t*2, 0ull);
}

// EMB: x += (sample @ embT) * sqrt(E). 64 blocks = 8 e-tiles x 8 v-splits (K=1024).
__device__ void ph_EMB(int blk, unsigned short* rawbf, const unsigned short* __restrict__ eT,
    const unsigned short* __restrict__ sbf, float* __restrict__ x){
  const int t = threadIdx.x;
  const int et = blk & 7, v0 = (blk >> 3)*1024;
  for (int i = t*16; i < BB*1024; i += 4096){
    int r = i >> 10, c = i & 1023;
    const unsigned short* s = sbf + (size_t)r*VV + v0 + c;
    ull u0 = ld_cv(s), u1 = ld_cv(s+4), u2 = ld_cv(s+8), u3 = ld_cv(s+12);
    ull* dst = (ull*)(rawbf + r*EBP + c);
    dst[0] = u0; dst[1] = u1; dst[2] = u2; dst[3] = u3;
  }
  __syncthreads();
  const int wv = t >> 6, lane = t & 63;
  const int lm = lane & 15, kg = lane >> 4;
  const int e0w = et*64 + wv*16;
  const unsigned short* ar  = eT + (size_t)(e0w + lm)*VV + v0 + kg*8;
  const unsigned short* b0r = rawbf + lm*EBP + kg*8;
  const unsigned short* b1r = rawbf + (lm+16)*EBP + kg*8;
  f32x4 acc0 = {0.f,0.f,0.f,0.f}, acc1 = {0.f,0.f,0.f,0.f};
  #pragma unroll 8
  for (int ks = 0; ks < 32; ++ks){
    bf16x8 a  = *reinterpret_cast<const bf16x8*>(ar + ks*32);
    bf16x8 b0 = *reinterpret_cast<const bf16x8*>(b0r + ks*32);
    bf16x8 b1 = *reinterpret_cast<const bf16x8*>(b1r + ks*32);
    acc0 = mfma16(a, b0, acc0);
    acc1 = mfma16(a, b1, acc1);
  }
  #pragma unroll
  for (int r = 0; r < 4; ++r){
    const int e = e0w + kg*4 + r;
    atomicAdd(&x[lm*EE + e], acc0[r]*SCALE_EMB);
    atomicAdd(&x[(lm+16)*EE + e], acc1[r]*SCALE_EMB);
  }
}

// ---------------- the megakernel ----------------

struct MegaParams {
  float* x; float* xln; float* o2a; float* o2b; float* yacc0; float* yacc1; float* logits;
  const float* cac;
  float* kcache; float* vcache;
  unsigned short* Hb; unsigned short* sbf;
  const unsigned short* wqkvb; const unsigned short* owb;
  const unsigned short* w1b; const unsigned short* w2b;
  const unsigned short* outwb; const unsigned short* eTb;
  const float* saqb; const float* saob;
  const float* l1g; const float* l1b; const float* l2g; const float* l2b;
  const float* l3g; const float* l3b;
  const float* b1; const float* b2; const float* outb; const float* gumb;
  float* dseq; float* ddist;
  unsigned* evt;
};

__global__ __launch_bounds__(256, 1) void k_mega(MegaParams P){
  __shared__ __align__(16) unsigned char SMEM[110080];
  unsigned short* xs = (unsigned short*)SMEM;                  // 33280 B  [32][520] bf16
  float* rawf        = (float*)(SMEM + 33280);                 // 66048 B  [32][516] f32
  unsigned short* rawbf = (unsigned short*)(SMEM + 33280);     //   (alias, [32][1032] bf16)
  float* qs  = (float*)(SMEM + 99328);                         //  8704 B  [32][68] f32
  float* att = (float*)(SMEM + 108032);                        //  2048 B
  const int blk = blockIdx.x;
  float* yp[2] = { P.yacc0, P.yacc1 };
  float* o2p[2] = { P.o2a, P.o2b };

  for (int step = 0; step < TT; ++step){
    const int tpos = step, tlen = step + 1;
    const int base = step*NPH_STEP;
    for (int l = 0; l < LL; ++l){
      const int use_ln = (l > 0);
      const int eA = base + l*3, eB = eA + 1, eC = eA + 2;
      float* ycur = yp[l & 1];
      float* o2cur = o2p[l & 1];
      const float* yprev = yp[(l-1) & 1];
      if (blk < NHD){
        if (l == 0){ if (step > 0) evt_wait(P.evt + (base - 1)*EVS, 64); }
        else         evt_wait(P.evt + (eA - 1)*EVS, 32);
        ph_A(blk, xs, qs, att, P.x, yprev,
             P.l3g + (use_ln ? (l-1)*EE : 0), P.l3b + (use_ln ? (l-1)*EE : 0), use_ln,
             P.wqkvb + (size_t)l*3*EE*EE, P.saqb + (size_t)l*3*EE,
             P.owb + (size_t)l*EE*EE,
             P.kcache + (size_t)l*BB*EE*TT, P.vcache + (size_t)l*BB*EE*TT,
             P.xln, o2cur, tpos, tlen);
        evt_post(P.evt + eA*EVS);
      }
      if (blk < 32){
        evt_wait(P.evt + eA*EVS, 8);
        ph_B(blk, xs, rawf, o2cur, use_ln ? P.xln : P.x,
             P.saob + (size_t)l*EE, P.cac + (size_t)l*BB*EE,
             P.l1g + l*EE, P.l1b + l*EE, P.l2g + l*EE, P.l2b + l*EE, P.b2 + l*EE,
             P.w1b + (size_t)l*FFD*EE, P.b1 + l*FFD, P.Hb, ycur);
        evt_post(P.evt + eB*EVS);
        evt_wait(P.evt + eB*EVS, 32);
        ph_C(blk, xs, P.Hb, P.w2b + (size_t)l*EE*FFD, ycur, o2cur);
        evt_post(P.evt + eC*EVS);
      }
    }
    // LOG (all 128 blocks)
    evt_wait(P.evt + (base + 11)*EVS, 32);
    ph_LOG(blk, xs, yp[1], P.l3g + 3*EE, P.l3b + 3*EE, P.outwb, P.outb, P.logits);
    evt_post(P.evt + (base + 12)*EVS);
    // SM (32 blocks)
    if (blk < 32){
      evt_wait(P.evt + (base + 12)*EVS, 128);
      ph_SM(blk, att, P.logits, P.gumb + (size_t)step*BB*VV,
            P.dseq, P.ddist + (size_t)step*BB*VV, P.sbf, P.x, step);
      evt_post(P.evt + (base + 13)*EVS);
    }
    // EMB (64 blocks)
    if (blk < 64){
      evt_wait(P.evt + (base + 13)*EVS, 32);
      ph_EMB(blk, rawbf, P.eTb, P.sbf, P.x);
      evt_post(P.evt + (base + 14)*EVS);
    }
  }
}

// ---------------- host ----------------
extern "C" void kernel_launch(void* const* d_in, const int* in_sizes, int n_in,
                              void* d_out, int out_size, void* d_ws, size_t ws_size,
                              hipStream_t stream){
  (void)in_sizes; (void)n_in; (void)out_size; (void)ws_size;
  const float* enc  = (const float*)d_in[0];
  const float* spec = (const float*)d_in[1];
  const float* embw = (const float*)d_in[2];
  const float* outw = (const float*)d_in[3];
  const float* outb = (const float*)d_in[4];
  const float* gumb = (const float*)d_in[5];
  const float* saqw = (const float*)d_in[6];
  const float* saqb = (const float*)d_in[7];
  const float* saow = (const float*)d_in[8];
  const float* saob = (const float*)d_in[9];
  const float* caqw = (const float*)d_in[10];
  const float* caqb = (const float*)d_in[11];
  const float* caow = (const float*)d_in[12];
  const float* caob = (const float*)d_in[13];
  const float* l1g  = (const float*)d_in[14];
  const float* l1b  = (const float*)d_in[15];
  const float* l2g  = (const float*)d_in[16];
  const float* l2b  = (const float*)d_in[17];
  const float* l3g  = (const float*)d_in[18];
  const float* l3b  = (const float*)d_in[19];
  const float* w1   = (const float*)d_in[20];
  const float* b1   = (const float*)d_in[21];
  const float* w2   = (const float*)d_in[22];
  const float* b2   = (const float*)d_in[23];

  float* dout = (float*)d_out;
  float* dseq = dout;
  float* ddistbase = dout + (size_t)BB*(TT+1)*VV;

  unsigned char* p = (unsigned char*)d_ws;
  auto alloc = [&](size_t bytes) -> void* {
    void* r = (void*)p; p += (bytes + 255) & ~(size_t)255; return r;
  };
  float* x      = (float*)alloc(BB*EE*4);
  float* xln    = (float*)alloc(BB*EE*4);
  float* o2a    = (float*)alloc(BB*EE*4);
  float* o2b    = (float*)alloc(BB*EE*4);
  float* yacc0  = (float*)alloc(BB*EE*4);
  float* yacc1  = (float*)alloc(BB*EE*4);
  float* logits = (float*)alloc((size_t)BB*VV*4);
  float* venc   = (float*)alloc((size_t)LL*BB*EE*4);
  float* cac    = (float*)alloc((size_t)LL*BB*EE*4);
  float* kcache = (float*)alloc((size_t)LL*BB*EE*TT*4);
  float* vcache = (float*)alloc((size_t)LL*BB*EE*TT*4);
  unsigned short* Hb    = (unsigned short*)alloc(BB*FFD*2);
  unsigned short* sbf   = (unsigned short*)alloc((size_t)BB*VV*2);
  unsigned short* wqkvb = (unsigned short*)alloc((size_t)LL*3*EE*EE*2);
  unsigned short* owb   = (unsigned short*)alloc((size_t)LL*EE*EE*2);
  unsigned short* w1b   = (unsigned short*)alloc((size_t)LL*FFD*EE*2);
  unsigned short* w2b   = (unsigned short*)alloc((size_t)LL*FFD*EE*2);
  unsigned short* outwb = (unsigned short*)alloc((size_t)VV*EE*2);
  unsigned short* eTb   = (unsigned short*)alloc((size_t)EE*VV*2);
  unsigned* evt = (unsigned*)alloc((size_t)NPH_STEP*TT*EVS*4);

  // prologue: init (+o2/event reset), cross-attn constants, bf16 weight conversions
  // k_init coverage: 262144 (dseq) + 16384 (x) + 16384 (o2a) + 16384 (o2b) + 61440 (evt)
  k_init<<<1456, 256, 0, stream>>>(spec, dseq, x, o2a, o2b, evt);
  k_penc<<<32, 256, 0, stream>>>(enc, caqw, caqb, venc);
  k_pca<<<32, 256, 0, stream>>>(venc, caow, caob, cac);
  k_cvt<<<(LL*3*EE*EE/4 + 255)/256, 256, 0, stream>>>(saqw, wqkvb, LL*3*EE*EE/4);
  k_cvt<<<(LL*EE*EE/4 + 255)/256, 256, 0, stream>>>(saow, owb, LL*EE*EE/4);
  k_cvt<<<(LL*FFD*EE/4 + 255)/256, 256, 0, stream>>>(w1, w1b, LL*FFD*EE/4);
  k_cvt<<<(LL*FFD*EE/4 + 255)/256, 256, 0, stream>>>(w2, w2b, LL*FFD*EE/4);
  k_cvt<<<(VV*EE/4 + 255)/256, 256, 0, stream>>>(outw, outwb, VV*EE/4);
  k_embT<<<1024, 256, 0, stream>>>(embw, eTb);

  MegaParams mp;
  mp.x = x; mp.xln = xln; mp.o2a = o2a; mp.o2b = o2b;
  mp.yacc0 = yacc0; mp.yacc1 = yacc1; mp.logits = logits;
  mp.cac = cac; mp.kcache = kcache; mp.vcache = vcache;
  mp.Hb = Hb; mp.sbf = sbf;
  mp.wqkvb = wqkvb; mp.owb = owb; mp.w1b = w1b; mp.w2b = w2b;
  mp.outwb = outwb; mp.eTb = eTb;
  mp.saqb = saqb; mp.saob = saob;
  mp.l1g = l1g; mp.l1b = l1b; mp.l2g = l2g; mp.l2b = l2b;
  mp.l3g = l3g; mp.l3b = l3b;
  mp.b1 = b1; mp.b2 = b2; mp.outb = outb; mp.gumb = gumb;
  mp.dseq = dseq; mp.ddist = ddistbase;
  mp.evt = evt;

  // 128 persistent blocks, 110KB LDS -> 1 block/CU, all co-resident on 256 CUs.
  // Cross-block ordering via one-sided per-phase event counters (1KB-spread slots).
  k_mega<<<GRID_MEGA, 256, 0, stream>>>(mp);
}

// Round 7
// 4543.475 us; speedup vs baseline: 1.4859x; 1.2407x over previous
//
#include <hip/hip_runtime.h>
#include <math.h>

#define BB 32
#define EE 512
#define VV 8192
#define TT 16
#define LL 4
#define FFD 2048
#define NHD 8
#define HDD 64
#define LDP 520   // padded LDS pitch (bf16 elems)
#define RWP 516   // padded LDS pitch (f32 elems)
#define OLP 72    // o_lds pitch (bf16)
#define SCALE_EMB 22.627416997969522f

typedef __attribute__((ext_vector_type(8))) short bf16x8;
typedef __attribute__((ext_vector_type(4))) float f32x4;
typedef unsigned long long ull;

__device__ __forceinline__ f32x4 mfma16(bf16x8 a, bf16x8 b, f32x4 c){
  return __builtin_amdgcn_mfma_f32_16x16x32_bf16(a, b, c, 0, 0, 0);
}

// ---------------- helpers ----------------
__device__ __forceinline__ float wave_sum(float v){
  for (int o = 32; o; o >>= 1) v += __shfl_down(v, o);
  return __shfl(v, 0);
}
__device__ __forceinline__ unsigned short f_to_bf(float f){
  unsigned u = __float_as_uint(f);
  unsigned r = (u + 0x7fffu + ((u >> 16) & 1u)) >> 16;
  return (unsigned short)r;
}
__device__ __forceinline__ float2 bf2_to_f2(const unsigned short* p){
  unsigned u = *(const unsigned*)p;
  float2 r;
  r.x = __uint_as_float(u << 16);
  r.y = __uint_as_float(u & 0xffff0000u);
  return r;
}
union UF { ull u; unsigned short s[4]; };
__device__ __forceinline__ ull pkbf4(float a, float b, float c, float d){
  UF x; x.s[0] = f_to_bf(a); x.s[1] = f_to_bf(b); x.s[2] = f_to_bf(c); x.s[3] = f_to_bf(d); return x.u;
}

// fp32 VALU GEMM core (one-off prologue kernels k_penc/k_pca)
__device__ __forceinline__ void gemm_chunk(const float* __restrict__ wrow0, int ldw,
    const unsigned short* xs, float* wt, float acc[4][2]){
  const int t = threadIdx.x, fg = t & 15, bg = t >> 4;
  #pragma unroll 1
  for (int c = 0; c < 8; ++c){
    const int k0 = c*64;
    __syncthreads();
    {
      int i = t*4;
      #pragma unroll
      for (int p = 0; p < 4; ++p, i += 1024){
        const int fr = i >> 6, kk = i & 63;
        float4 v = *(const float4*)(wrow0 + (size_t)fr*ldw + k0 + kk);
        wt[(kk+0)*68 + fr] = v.x;
        wt[(kk+1)*68 + fr] = v.y;
        wt[(kk+2)*68 + fr] = v.z;
        wt[(kk+3)*68 + fr] = v.w;
      }
    }
    __syncthreads();
    const unsigned short* xr0 = xs + (bg*2)*EE + k0;
    const unsigned short* xr1 = xr0 + EE;
    #pragma unroll 8
    for (int k = 0; k < 64; k += 2){
      float w0[4], w1[4];
      *(float4*)w0 = *(const float4*)(wt + (k+0)*68 + fg*4);
      *(float4*)w1 = *(const float4*)(wt + (k+1)*68 + fg*4);
      float2 xv0 = bf2_to_f2(xr0 + k);
      float2 xv1 = bf2_to_f2(xr1 + k);
      #pragma unroll
      for (int i = 0; i < 4; ++i){
        acc[i][0] += w0[i]*xv0.x + w1[i]*xv0.y;
        acc[i][1] += w0[i]*xv1.x + w1[i]*xv1.y;
      }
    }
  }
}

// Stage [B,E] activations into padded-LDS bf16, optional pending LN3 from ybuf.
// If xlnout != null also materialize the LN'd fp32 rows. (R0-proven)
__device__ __forceinline__ void stage_x_p(unsigned short* xs,
    const float* __restrict__ xraw, const float* __restrict__ ybuf,
    const float* __restrict__ g, const float* __restrict__ bt, int use_ln,
    float* __restrict__ xlnout){
  if (!use_ln){
    for (int i = threadIdx.x; i < BB*EE; i += 256){
      int r = i >> 9, c = i & 511;
      xs[r*LDP + c] = f_to_bf(xraw[i]);
    }
  } else {
    const int lane = threadIdx.x & 63, wv = threadIdx.x >> 6;
    for (int r = wv*8; r < wv*8 + 8; ++r){
      float vals[8]; float s = 0.f, s2 = 0.f;
      #pragma unroll
      for (int j = 0; j < 8; ++j){
        float v = ybuf[r*EE + lane + j*64];
        vals[j] = v; s += v; s2 += v*v;
      }
      s = wave_sum(s); s2 = wave_sum(s2);
      float m = s * (1.f/EE);
      float inv = rsqrtf(s2*(1.f/EE) - m*m + 1e-5f);
      #pragma unroll
      for (int j = 0; j < 8; ++j){
        int c = lane + j*64;
        float v = (vals[j]-m)*inv*g[c] + bt[c];
        xs[r*LDP + c] = f_to_bf(v);
        if (xlnout) xlnout[r*EE + c] = v;
      }
    }
  }
  __syncthreads();
}

// ---------------- prologue kernels (R0-proven) ----------------

__global__ __launch_bounds__(256) void k_init(const float* __restrict__ special,
    float* __restrict__ dseq, float* __restrict__ x, float* __restrict__ o2){
  int idx = blockIdx.x*256 + threadIdx.x;
  if (idx < BB*VV){
    int b = idx >> 13, v = idx & (VV-1);
    dseq[(size_t)b*((TT+1)*VV) + (size_t)TT*VV + v] = (v == 0) ? 1.f : 0.f;
  } else if (idx < BB*VV + BB*EE){
    int i = idx - BB*VV;
    x[i] = special[i & (EE-1)];
  } else if (idx < BB*VV + 2*BB*EE){
    o2[idx - BB*VV - BB*EE] = 0.f;
  }
}

__global__ __launch_bounds__(256) void k_penc(const float* __restrict__ enc,
    const float* __restrict__ w, const float* __restrict__ bias, float* __restrict__ venc){
  __shared__ unsigned short xs[BB*EE];
  __shared__ float wt[64*68];
  const int l = blockIdx.x >> 3, et = blockIdx.x & 7;
  for (int i = threadIdx.x; i < BB*EE; i += 256) xs[i] = f_to_bf(enc[i]);
  const int t = threadIdx.x, fg = t & 15, bg = t >> 4;
  const int f0 = et*64;
  const float* wl = w + (size_t)l*3*EE*EE + (size_t)(2*EE + f0)*EE;
  const float* bl = bias + l*3*EE + 2*EE + f0;
  float acc[4][2];
  #pragma unroll
  for (int i = 0; i < 4; ++i){ float bv = bl[fg*4+i]; acc[i][0] = bv; acc[i][1] = bv; }
  gemm_chunk(wl, EE, xs, wt, acc);
  #pragma unroll
  for (int i = 0; i < 4; ++i)
    #pragma unroll
    for (int j = 0; j < 2; ++j)
      venc[(size_t)l*BB*EE + (bg*2+j)*EE + f0 + fg*4 + i] = acc[i][j];
}

__global__ __launch_bounds__(256) void k_pca(const float* __restrict__ venc,
    const float* __restrict__ w, const float* __restrict__ bias, float* __restrict__ cac){
  __shared__ unsigned short xs[BB*EE];
  __shared__ float wt[64*68];
  const int l = blockIdx.x >> 3, et = blockIdx.x & 7;
  const float* vin = venc + (size_t)l*BB*EE;
  for (int i = threadIdx.x; i < BB*EE; i += 256) xs[i] = f_to_bf(vin[i]);
  const int t = threadIdx.x, fg = t & 15, bg = t >> 4;
  const int f0 = et*64;
  const float* wl = w + (size_t)l*EE*EE + (size_t)f0*EE;
  const float* bl = bias + l*EE + f0;
  float acc[4][2];
  #pragma unroll
  for (int i = 0; i < 4; ++i){ float bv = bl[fg*4+i]; acc[i][0] = bv; acc[i][1] = bv; }
  gemm_chunk(wl, EE, xs, wt, acc);
  #pragma unroll
  for (int i = 0; i < 4; ++i)
    #pragma unroll
    for (int j = 0; j < 2; ++j)
      cac[(size_t)l*BB*EE + (bg*2+j)*EE + f0 + fg*4 + i] = acc[i][j];
}

__global__ __launch_bounds__(256) void k_cvt(const float* __restrict__ s,
    unsigned short* __restrict__ d, int n4){
  int i = blockIdx.x*256 + threadIdx.x;
  if (i < n4){
    float4 v = ((const float4*)s)[i];
    ushort4 o;
    o.x = f_to_bf(v.x); o.y = f_to_bf(v.y); o.z = f_to_bf(v.z); o.w = f_to_bf(v.w);
    ((ushort4*)d)[i] = o;
  }
}

__global__ __launch_bounds__(256) void k_embT(const float* __restrict__ emb,
    unsigned short* __restrict__ eT){
  __shared__ unsigned short tl[64][68];
  const int vt = blockIdx.x >> 3, et = blockIdx.x & 7;
  const int v0 = vt*64, e0 = et*64;
  for (int i = threadIdx.x; i < 64*64; i += 256){
    int vv = i >> 6, ee = i & 63;
    tl[vv][ee] = f_to_bf(emb[(size_t)(v0+vv)*EE + e0 + ee]);
  }
  __syncthreads();
  for (int i = threadIdx.x; i < 64*64; i += 256){
    int ee = i >> 6, vv = i & 63;
    eT[(size_t)(e0+ee)*VV + v0 + vv] = tl[vv][ee];
  }
}

// ---------------- per-step kernels ----------------

// A: qkv (head h chunk, 3x64 feats) + attention for head h + out-projection
// k-split (head h's 64-col slice of W_out) -> atomicAdd partials into o2.
// grid 8. Replaces R0's {qkv(24), attn(32), outp(8)}. Numerics = R5 ph_A (refcheck'd).
__global__ __launch_bounds__(256) void k_A(
    const float* __restrict__ x, const float* __restrict__ ybuf,
    const float* __restrict__ lng, const float* __restrict__ lnb, int use_ln,
    const unsigned short* __restrict__ Wb, const float* __restrict__ bias,
    const unsigned short* __restrict__ owb_l,
    float* __restrict__ kcl, float* __restrict__ vcl,
    float* __restrict__ xln, float* __restrict__ o2,
    int tpos, int tlen){
  __shared__ unsigned short xs[BB*LDP];
  __shared__ __align__(16) float qs[BB*68];
  __shared__ float att[BB*16];
  const int h = blockIdx.x;
  stage_x_p(xs, x, ybuf, lng, lnb, use_ln, (use_ln && h == 0) ? xln : nullptr);
  const int t = threadIdx.x, wv = t >> 6, lane = t & 63;
  const int lm = lane & 15, kg = lane >> 4;
  const unsigned short* b0r = xs + lm*LDP + kg*8;
  const unsigned short* b1r = xs + (lm+16)*LDP + kg*8;
  #pragma unroll
  for (int c = 0; c < 3; ++c){
    const int fbase = c*EE + h*64 + wv*16;
    const unsigned short* ar = Wb + (size_t)(fbase + lm)*EE + kg*8;
    f32x4 acc0 = {0.f,0.f,0.f,0.f}, acc1 = {0.f,0.f,0.f,0.f};
    #pragma unroll 4
    for (int ks = 0; ks < 16; ++ks){
      bf16x8 a  = *reinterpret_cast<const bf16x8*>(ar + ks*32);
      bf16x8 b0 = *reinterpret_cast<const bf16x8*>(b0r + ks*32);
      bf16x8 b1 = *reinterpret_cast<const bf16x8*>(b1r + ks*32);
      acc0 = mfma16(a, b0, acc0);
      acc1 = mfma16(a, b1, acc1);
    }
    #pragma unroll
    for (int r = 0; r < 4; ++r){
      const int frel = wv*16 + kg*4 + r;
      const float bv = bias[c*EE + h*64 + frel];
      float v0 = acc0[r] + bv, v1 = acc1[r] + bv;
      if (c == 0){
        qs[lm*68 + frel] = v0;
        qs[(lm+16)*68 + frel] = v1;
      } else if (c == 1){
        kcl[((lm*NHD + h)*TT + tpos)*HDD + frel] = v0;
        kcl[(((lm+16)*NHD + h)*TT + tpos)*HDD + frel] = v1;
      } else {
        vcl[((lm*NHD + h)*TT + tpos)*HDD + frel] = v0;
        vcl[(((lm+16)*NHD + h)*TT + tpos)*HDD + frel] = v1;
      }
    }
  }
  __syncthreads();
  // scores
  #pragma unroll
  for (int pp = 0; pp < 2; ++pp){
    const int p = t + pp*256;
    const int b = p >> 4, j = p & 15;
    if (j < tlen){
      const float* qrow = qs + b*68;
      const float* krow = kcl + ((b*NHD + h)*TT + j)*HDD;
      float a = 0.f;
      #pragma unroll
      for (int d = 0; d < HDD; d += 4){
        float4 qv = *(const float4*)(qrow + d);
        float4 kv = *(const float4*)(krow + d);
        a += qv.x*kv.x + qv.y*kv.y + qv.z*kv.z + qv.w*kv.w;
      }
      att[b*16 + j] = a*0.125f;
    }
  }
  __syncthreads();
  if (t < 32){
    const int b = t;
    float m = -1e30f;
    for (int j = 0; j < tlen; ++j) m = fmaxf(m, att[b*16 + j]);
    float s = 0.f;
    for (int j = 0; j < tlen; ++j) s += __expf(att[b*16 + j] - m);
    float inv = 1.f/s;
    for (int j = 0; j < tlen; ++j) att[b*16 + j] = __expf(att[b*16 + j] - m)*inv;
  }
  __syncthreads();
  // PV -> o_lds (bf16, pitch OLP); aliases qs (all qs reads complete)
  unsigned short* o_lds = (unsigned short*)qs;
  {
    const int b = t >> 3, d0 = (t & 7)*8;
    float acc[8];
    #pragma unroll
    for (int i = 0; i < 8; ++i) acc[i] = 0.f;
    const float* vrow = vcl + ((b*NHD + h)*TT)*HDD + d0;
    for (int j = 0; j < tlen; ++j){
      const float a = att[b*16 + j];
      float4 v0 = *(const float4*)(vrow + j*HDD);
      float4 v1 = *(const float4*)(vrow + j*HDD + 4);
      acc[0] += a*v0.x; acc[1] += a*v0.y; acc[2] += a*v0.z; acc[3] += a*v0.w;
      acc[4] += a*v1.x; acc[5] += a*v1.y; acc[6] += a*v1.z; acc[7] += a*v1.w;
    }
    *(ull*)(o_lds + b*OLP + d0)     = pkbf4(acc[0], acc[1], acc[2], acc[3]);
    *(ull*)(o_lds + b*OLP + d0 + 4) = pkbf4(acc[4], acc[5], acc[6], acc[7]);
  }
  __syncthreads();
  // out-projection partial: o_h[32,64] x Wout[:, h*64:h*64+64]^T -> atomicAdd o2
  const unsigned short* ob0 = o_lds + lm*OLP + kg*8;
  const unsigned short* ob1 = o_lds + (lm+16)*OLP + kg*8;
  #pragma unroll
  for (int ft = 0; ft < 8; ++ft){
    const int f0 = wv*128 + ft*16;
    const unsigned short* ar = owb_l + (size_t)(f0 + lm)*EE + h*HDD + kg*8;
    f32x4 a0 = {0.f,0.f,0.f,0.f}, a1 = {0.f,0.f,0.f,0.f};
    #pragma unroll
    for (int ks = 0; ks < 2; ++ks){
      bf16x8 a  = *reinterpret_cast<const bf16x8*>(ar + ks*32);
      bf16x8 x0 = *reinterpret_cast<const bf16x8*>(ob0 + ks*32);
      bf16x8 x1 = *reinterpret_cast<const bf16x8*>(ob1 + ks*32);
      a0 = mfma16(a, x0, a0);
      a1 = mfma16(a, x1, a1);
    }
    #pragma unroll
    for (int r = 0; r < 4; ++r){
      const int f = f0 + kg*4 + r;
      atomicAdd(&o2[lm*EE + f], a0[r]);
      atomicAdd(&o2[(lm+16)*EE + f], a1[r]);
    }
  }
}

// B: stage (o2 + resid + ob) -> LDS f32, LN1(+cac) -> LN2 -> ffn1 GEMM (64 H-feats).
// blk0 also writes y base = LN2out + b2bias. grid 32. (R5 ph_B, plain memory)
__global__ __launch_bounds__(256) void k_B(
    const float* __restrict__ o2, const float* __restrict__ resid,
    const float* __restrict__ ob, const float* __restrict__ cac,
    const float* __restrict__ g1, const float* __restrict__ b1g,
    const float* __restrict__ g2, const float* __restrict__ b2g,
    const float* __restrict__ b2bias,
    const unsigned short* __restrict__ w1b, const float* __restrict__ b1bias,
    unsigned short* __restrict__ Hb, float* __restrict__ ybuf){
  __shared__ unsigned short xs[BB*LDP];
  __shared__ __align__(16) float rawf[BB*RWP];
  const int t = threadIdx.x, blk = blockIdx.x;
  for (int i = t*4; i < BB*EE; i += 1024){
    const int r = i >> 9, c = i & 511;
    float4 a  = *(const float4*)(o2 + i);
    float4 rr = *(const float4*)(resid + i);
    float4 ov = *(const float4*)(ob + c);
    rawf[r*RWP + c]     = a.x + rr.x + ov.x;
    rawf[r*RWP + c + 1] = a.y + rr.y + ov.y;
    rawf[r*RWP + c + 2] = a.z + rr.z + ov.z;
    rawf[r*RWP + c + 3] = a.w + rr.w + ov.w;
  }
  __syncthreads();
  const int wv = t >> 6, lane = t & 63;
  const int lm = lane & 15, kg = lane >> 4;
  {
    float* yi = (blk == 0) ? ybuf : nullptr;
    const int c0 = lane*4, c1 = 256 + lane*4;
    for (int r = wv*8; r < wv*8 + 8; ++r){
      float v[8];
      *(float4*)(v+0) = *(const float4*)(rawf + r*RWP + c0);
      *(float4*)(v+4) = *(const float4*)(rawf + r*RWP + c1);
      float s = 0.f, s2 = 0.f;
      #pragma unroll
      for (int j = 0; j < 8; ++j){ s += v[j]; s2 += v[j]*v[j]; }
      s = wave_sum(s); s2 = wave_sum(s2);
      float m = s*(1.f/EE), inv = rsqrtf(s2*(1.f/EE) - m*m + 1e-5f);
      float4 ca0 = *(const float4*)(cac + (size_t)r*EE + c0);
      float4 ca1 = *(const float4*)(cac + (size_t)r*EE + c1);
      float nv[8]; float u = 0.f, u2 = 0.f;
      nv[0] = (v[0]-m)*inv*g1[c0+0] + b1g[c0+0] + ca0.x;
      nv[1] = (v[1]-m)*inv*g1[c0+1] + b1g[c0+1] + ca0.y;
      nv[2] = (v[2]-m)*inv*g1[c0+2] + b1g[c0+2] + ca0.z;
      nv[3] = (v[3]-m)*inv*g1[c0+3] + b1g[c0+3] + ca0.w;
      nv[4] = (v[4]-m)*inv*g1[c1+0] + b1g[c1+0] + ca1.x;
      nv[5] = (v[5]-m)*inv*g1[c1+1] + b1g[c1+1] + ca1.y;
      nv[6] = (v[6]-m)*inv*g1[c1+2] + b1g[c1+2] + ca1.z;
      nv[7] = (v[7]-m)*inv*g1[c1+3] + b1g[c1+3] + ca1.w;
      #pragma unroll
      for (int j = 0; j < 8; ++j){ u += nv[j]; u2 += nv[j]*nv[j]; }
      u = wave_sum(u); u2 = wave_sum(u2);
      float m2 = u*(1.f/EE), inv2 = rsqrtf(u2*(1.f/EE) - m2*m2 + 1e-5f);
      float o0 = (nv[0]-m2)*inv2*g2[c0+0] + b2g[c0+0];
      float o1 = (nv[1]-m2)*inv2*g2[c0+1] + b2g[c0+1];
      float o2v = (nv[2]-m2)*inv2*g2[c0+2] + b2g[c0+2];
      float o3 = (nv[3]-m2)*inv2*g2[c0+3] + b2g[c0+3];
      float o4 = (nv[4]-m2)*inv2*g2[c1+0] + b2g[c1+0];
      float o5 = (nv[5]-m2)*inv2*g2[c1+1] + b2g[c1+1];
      float o6 = (nv[6]-m2)*inv2*g2[c1+2] + b2g[c1+2];
      float o7 = (nv[7]-m2)*inv2*g2[c1+3] + b2g[c1+3];
      *(ull*)(xs + r*LDP + c0) = pkbf4(o0, o1, o2v, o3);
      *(ull*)(xs + r*LDP + c1) = pkbf4(o4, o5, o6, o7);
      if (yi){
        float4 w0, w1;
        w0.x = o0 + b2bias[c0+0]; w0.y = o1 + b2bias[c0+1];
        w0.z = o2v + b2bias[c0+2]; w0.w = o3 + b2bias[c0+3];
        w1.x = o4 + b2bias[c1+0]; w1.y = o5 + b2bias[c1+1];
        w1.z = o6 + b2bias[c1+2]; w1.w = o7 + b2bias[c1+3];
        *(float4*)(yi + (size_t)r*EE + c0) = w0;
        *(float4*)(yi + (size_t)r*EE + c1) = w1;
      }
    }
    __syncthreads();
  }
  {
    const int f0w = blk*64 + wv*16;
    const unsigned short* ar = w1b + (size_t)(f0w + lm)*EE + kg*8;
    const unsigned short* b0r = xs + lm*LDP + kg*8;
    const unsigned short* b1r = xs + (lm+16)*LDP + kg*8;
    f32x4 acc0 = {0.f,0.f,0.f,0.f}, acc1 = {0.f,0.f,0.f,0.f};
    #pragma unroll 4
    for (int ks = 0; ks < 16; ++ks){
      bf16x8 a  = *reinterpret_cast<const bf16x8*>(ar + ks*32);
      bf16x8 b0 = *reinterpret_cast<const bf16x8*>(b0r + ks*32);
      bf16x8 b1 = *reinterpret_cast<const bf16x8*>(b1r + ks*32);
      acc0 = mfma16(a, b0, acc0);
      acc1 = mfma16(a, b1, acc1);
    }
    const int fb = f0w + kg*4;
    float h0[4], h1[4];
    #pragma unroll
    for (int r = 0; r < 4; ++r){
      const float bv = b1bias[fb + r];
      float v0 = acc0[r] + bv, v1 = acc1[r] + bv;
      h0[r] = 0.5f*v0*(1.f + erff(v0*0.70710678118654752f));
      h1[r] = 0.5f*v1*(1.f + erff(v1*0.70710678118654752f));
    }
    *(ull*)(Hb + lm*FFD + fb)      = pkbf4(h0[0], h0[1], h0[2], h0[3]);
    *(ull*)(Hb + (lm+16)*FFD + fb) = pkbf4(h1[0], h1[1], h1[2], h1[3]);
  }
}

// C: ffn2 k-split x4, atomicAdd into y; zero this block's o2 slice for next layer.
// grid 32. (R5 ph_C, plain memory)
__global__ __launch_bounds__(256) void k_C(
    const unsigned short* __restrict__ Hb, const unsigned short* __restrict__ w2b,
    float* __restrict__ ybuf, float* __restrict__ o2z){
  __shared__ unsigned short xs[BB*LDP];
  const int t = threadIdx.x, blk = blockIdx.x;
  const int k0 = (blk >> 3)*512;
  for (int i = t*16; i < BB*512; i += 4096){
    int r = i >> 9, c = i & 511;
    const unsigned short* s = Hb + (size_t)r*FFD + k0 + c;
    ull* dst = (ull*)(xs + r*LDP + c);
    dst[0] = *(const ull*)s;      dst[1] = *(const ull*)(s+4);
    dst[2] = *(const ull*)(s+8);  dst[3] = *(const ull*)(s+12);
  }
  __syncthreads();
  const int wv = t >> 6, lane = t & 63;
  const int lm = lane & 15, kg = lane >> 4;
  const int f0w = (blk & 7)*64 + wv*16;
  const unsigned short* ar = w2b + (size_t)(f0w + lm)*FFD + k0 + kg*8;
  const unsigned short* b0r = xs + lm*LDP + kg*8;
  const unsigned short* b1r = xs + (lm+16)*LDP + kg*8;
  f32x4 acc0 = {0.f,0.f,0.f,0.f}, acc1 = {0.f,0.f,0.f,0.f};
  #pragma unroll 4
  for (int ks = 0; ks < 16; ++ks){
    bf16x8 a  = *reinterpret_cast<const bf16x8*>(ar + ks*32);
    bf16x8 b0 = *reinterpret_cast<const bf16x8*>(b0r + ks*32);
    bf16x8 b1 = *reinterpret_cast<const bf16x8*>(b1r + ks*32);
    acc0 = mfma16(a, b0, acc0);
    acc1 = mfma16(a, b1, acc1);
  }
  #pragma unroll
  for (int r = 0; r < 4; ++r){
    const int f = f0w + kg*4 + r;
    atomicAdd(&ybuf[lm*EE + f], acc0[r]);
    atomicAdd(&ybuf[(lm+16)*EE + f], acc1[r]);
  }
  float2 z; z.x = 0.f; z.y = 0.f;
  *(float2*)(o2z + blk*512 + t*2) = z;
}

// logits = LN3(y) @ out_w.T + out_b. grid 128. (R0-proven)
__global__ __launch_bounds__(256) void k_logits_m(
    const float* __restrict__ ybuf, const float* __restrict__ lng, const float* __restrict__ lnb,
    const unsigned short* __restrict__ Wb, const float* __restrict__ bias,
    float* __restrict__ logits){
  __shared__ unsigned short xs[BB*LDP];
  stage_x_p(xs, nullptr, ybuf, lng, lnb, 1, nullptr);
  const int t = threadIdx.x, w = t >> 6, l = t & 63;
  const int lm = l & 15, kg = l >> 4;
  const int f0w = blockIdx.x*64 + w*16;
  const unsigned short* ar = Wb + (size_t)(f0w + lm)*EE + kg*8;
  const unsigned short* b0r = xs + lm*LDP + kg*8;
  const unsigned short* b1r = xs + (lm+16)*LDP + kg*8;
  f32x4 acc0 = {0.f,0.f,0.f,0.f}, acc1 = {0.f,0.f,0.f,0.f};
  #pragma unroll 4
  for (int ks = 0; ks < 16; ++ks){
    bf16x8 a  = *reinterpret_cast<const bf16x8*>(ar + ks*32);
    bf16x8 b0 = *reinterpret_cast<const bf16x8*>(b0r + ks*32);
    bf16x8 b1 = *reinterpret_cast<const bf16x8*>(b1r + ks*32);
    acc0 = mfma16(a, b0, acc0);
    acc1 = mfma16(a, b1, acc1);
  }
  #pragma unroll
  for (int r = 0; r < 4; ++r){
    const int f = f0w + kg*4 + r;
    const float bv = bias[f];
    logits[lm*VV + f]      = acc0[r] + bv;
    logits[(lm+16)*VV + f] = acc1[r] + bv;
  }
}

// dual softmax; writes distrib + gumbel sample, zeroes x. grid 32. (R0-proven)
__global__ __launch_bounds__(256) void k_softmax(const float* __restrict__ logits,
    const float* __restrict__ gum, float* __restrict__ dseq, float* __restrict__ ddist,
    unsigned short* __restrict__ sbf, float* __restrict__ x, int step){
  const int b = blockIdx.x, t = threadIdx.x, lane = t & 63, wv = t >> 6;
  __shared__ float red[8];
  const float* lr = logits + (size_t)b*VV;
  const float* gr = gum + (size_t)b*VV;
  float m1 = -1e30f, m2 = -1e30f;
  for (int i = t; i < VV; i += 256){
    float l = lr[i];
    m1 = fmaxf(m1, l);
    m2 = fmaxf(m2, l + gr[i]);
  }
  for (int o = 32; o; o >>= 1){ m1 = fmaxf(m1, __shfl_down(m1,o)); m2 = fmaxf(m2, __shfl_down(m2,o)); }
  if (lane == 0){ red[wv] = m1; red[4+wv] = m2; }
  __syncthreads();
  m1 = fmaxf(fmaxf(red[0],red[1]), fmaxf(red[2],red[3]));
  m2 = fmaxf(fmaxf(red[4],red[5]), fmaxf(red[6],red[7]));
  __syncthreads();
  float s1 = 0.f, s2 = 0.f;
  for (int i = t; i < VV; i += 256){
    float l = lr[i];
    s1 += __expf(l - m1);
    s2 += __expf(l + gr[i] - m2);
  }
  for (int o = 32; o; o >>= 1){ s1 += __shfl_down(s1,o); s2 += __shfl_down(s2,o); }
  if (lane == 0){ red[wv] = s1; red[4+wv] = s2; }
  __syncthreads();
  s1 = red[0]+red[1]+red[2]+red[3];
  s2 = red[4]+red[5]+red[6]+red[7];
  float r1 = 1.f/s1, r2 = 1.f/s2;
  float* dq = dseq + (size_t)b*((TT+1)*VV) + (size_t)step*VV;
  float* dd = ddist + (size_t)b*VV;
  for (int i = t; i < VV; i += 256){
    float l = lr[i];
    dd[i] = __expf(l - m1)*r1;
    float qv = __expf(l + gr[i] - m2)*r2;
    dq[i] = qv;
    sbf[(size_t)b*VV + i] = f_to_bf(qv);
  }
  for (int i = t; i < EE; i += 256) x[b*EE + i] = 0.f;
}

// x += (sample @ emb) * sqrt(E): k-split x8, atomics. grid 64. (R0-proven)
__global__ __launch_bounds__(256) void k_embed_m(
    const unsigned short* __restrict__ eT, const unsigned short* __restrict__ sbf,
    float* __restrict__ x){
  const int t = threadIdx.x, w = t >> 6, l = t & 63;
  const int lm = l & 15, kg = l >> 4;
  const int e0w = (blockIdx.x & 7)*64 + w*16;
  const int v0 = (blockIdx.x >> 3)*1024;
  const unsigned short* ar  = eT + (size_t)(e0w + lm)*VV + v0 + kg*8;
  const unsigned short* b0r = sbf + (size_t)lm*VV + v0 + kg*8;
  const unsigned short* b1r = sbf + (size_t)(lm+16)*VV + v0 + kg*8;
  f32x4 acc0 = {0.f,0.f,0.f,0.f}, acc1 = {0.f,0.f,0.f,0.f};
  #pragma unroll 8
  for (int ks = 0; ks < 32; ++ks){
    bf16x8 a  = *reinterpret_cast<const bf16x8*>(ar + ks*32);
    bf16x8 b0 = *reinterpret_cast<const bf16x8*>(b0r + ks*32);
    bf16x8 b1 = *reinterpret_cast<const bf16x8*>(b1r + ks*32);
    acc0 = mfma16(a, b0, acc0);
    acc1 = mfma16(a, b1, acc1);
  }
  #pragma unroll
  for (int r = 0; r < 4; ++r){
    const int e = e0w + kg*4 + r;
    atomicAdd(&x[lm*EE + e], acc0[r]*SCALE_EMB);
    atomicAdd(&x[(lm+16)*EE + e], acc1[r]*SCALE_EMB);
  }
}

// ---------------- host ----------------
extern "C" void kernel_launch(void* const* d_in, const int* in_sizes, int n_in,
                              void* d_out, int out_size, void* d_ws, size_t ws_size,
                              hipStream_t stream){
  (void)in_sizes; (void)n_in; (void)out_size; (void)ws_size;
  const float* enc  = (const float*)d_in[0];
  const float* spec = (const float*)d_in[1];
  const float* embw = (const float*)d_in[2];
  const float* outw = (const float*)d_in[3];
  const float* outb = (const float*)d_in[4];
  const float* gumb = (const float*)d_in[5];
  const float* saqw = (const float*)d_in[6];
  const float* saqb = (const float*)d_in[7];
  const float* saow = (const float*)d_in[8];
  const float* saob = (const float*)d_in[9];
  const float* caqw = (const float*)d_in[10];
  const float* caqb = (const float*)d_in[11];
  const float* caow = (const float*)d_in[12];
  const float* caob = (const float*)d_in[13];
  const float* l1g  = (const float*)d_in[14];
  const float* l1b  = (const float*)d_in[15];
  const float* l2g  = (const float*)d_in[16];
  const float* l2b  = (const float*)d_in[17];
  const float* l3g  = (const float*)d_in[18];
  const float* l3b  = (const float*)d_in[19];
  const float* w1   = (const float*)d_in[20];
  const float* b1   = (const float*)d_in[21];
  const float* w2   = (const float*)d_in[22];
  const float* b2   = (const float*)d_in[23];

  float* dout = (float*)d_out;
  float* dseq = dout;
  float* ddistbase = dout + (size_t)BB*(TT+1)*VV;

  unsigned char* p = (unsigned char*)d_ws;
  auto alloc = [&](size_t bytes) -> void* {
    void* r = (void*)p; p += (bytes + 255) & ~(size_t)255; return r;
  };
  float* x      = (float*)alloc(BB*EE*4);
  float* y      = (float*)alloc(BB*EE*4);
  float* xln    = (float*)alloc(BB*EE*4);
  float* o2     = (float*)alloc(BB*EE*4);
  float* logits = (float*)alloc((size_t)BB*VV*4);
  float* venc   = (float*)alloc((size_t)LL*BB*EE*4);
  float* cac    = (float*)alloc((size_t)LL*BB*EE*4);
  float* kcache = (float*)alloc((size_t)LL*BB*EE*TT*4);
  float* vcache = (float*)alloc((size_t)LL*BB*EE*TT*4);
  unsigned short* Hb    = (unsigned short*)alloc(BB*FFD*2);
  unsigned short* sbf   = (unsigned short*)alloc((size_t)BB*VV*2);
  unsigned short* wqkvb = (unsigned short*)alloc((size_t)LL*3*EE*EE*2);
  unsigned short* owb   = (unsigned short*)alloc((size_t)LL*EE*EE*2);
  unsigned short* w1b   = (unsigned short*)alloc((size_t)LL*FFD*EE*2);
  unsigned short* w2b   = (unsigned short*)alloc((size_t)LL*FFD*EE*2);
  unsigned short* outwb = (unsigned short*)alloc((size_t)VV*EE*2);
  unsigned short* eTb   = (unsigned short*)alloc((size_t)EE*VV*2);

  // prologue: init (dseq eos + x + o2 zero), cross-attn constants, weight conversions
  k_init<<<1152, 256, 0, stream>>>(spec, dseq, x, o2);
  k_penc<<<32, 256, 0, stream>>>(enc, caqw, caqb, venc);
  k_pca<<<32, 256, 0, stream>>>(venc, caow, caob, cac);
  k_cvt<<<(LL*3*EE*EE/4 + 255)/256, 256, 0, stream>>>(saqw, wqkvb, LL*3*EE*EE/4);
  k_cvt<<<(LL*EE*EE/4 + 255)/256, 256, 0, stream>>>(saow, owb, LL*EE*EE/4);
  k_cvt<<<(LL*FFD*EE/4 + 255)/256, 256, 0, stream>>>(w1, w1b, LL*FFD*EE/4);
  k_cvt<<<(LL*FFD*EE/4 + 255)/256, 256, 0, stream>>>(w2, w2b, LL*FFD*EE/4);
  k_cvt<<<(VV*EE/4 + 255)/256, 256, 0, stream>>>(outw, outwb, VV*EE/4);
  k_embT<<<1024, 256, 0, stream>>>(embw, eTb);

  // 15 launches/step (vs 23 in the 4817us baseline): A fuses qkv+attn+outp.
  for (int step = 0; step < TT; ++step){
    const int tpos = step, tlen = step + 1;
    for (int l = 0; l < LL; ++l){
      const int use_ln = (l > 0);
      const float* lg = l3g + (use_ln ? (l-1)*EE : 0);
      const float* lb = l3b + (use_ln ? (l-1)*EE : 0);
      float* kcl = kcache + (size_t)l*BB*EE*TT;
      float* vcl = vcache + (size_t)l*BB*EE*TT;
      const float* resid = use_ln ? xln : x;
      k_A<<<NHD, 256, 0, stream>>>(x, y, lg, lb, use_ln,
          wqkvb + (size_t)l*3*EE*EE, saqb + (size_t)l*3*EE,
          owb + (size_t)l*EE*EE, kcl, vcl, xln, o2, tpos, tlen);
      k_B<<<32, 256, 0, stream>>>(o2, resid, saob + (size_t)l*EE,
          cac + (size_t)l*BB*EE,
          l1g + l*EE, l1b + l*EE, l2g + l*EE, l2b + l*EE, b2 + l*EE,
          w1b + (size_t)l*FFD*EE, b1 + l*FFD, Hb, y);
      k_C<<<32, 256, 0, stream>>>(Hb, w2b + (size_t)l*EE*FFD, y, o2);
    }
    k_logits_m<<<128, 256, 0, stream>>>(y, l3g + 3*EE, l3b + 3*EE, outwb, outb, logits);
    k_softmax<<<32, 256, 0, stream>>>(logits, gumb + (size_t)step*BB*VV, dseq,
        ddistbase + (size_t)step*BB*VV, sbf, x, step);
    k_embed_m<<<64, 256, 0, stream>>>(eTb, sbf, x);
  }
}

// Round 8
// 4142.755 us; speedup vs baseline: 1.6297x; 1.0967x over previous
//
#include <hip/hip_runtime.h>
#include <math.h>

#define BB 32
#define EE 512
#define VV 8192
#define TT 16
#define LL 4
#define FFD 2048
#define NHD 8
#define HDD 64
#define LDP 520   // padded LDS pitch (bf16 elems)
#define RWP 516   // padded LDS pitch (f32 elems)
#define OLP 72    // small-tile LDS pitch (bf16): 144B rows, 16B-aligned
#define SCALE_EMB 22.627416997969522f

typedef __attribute__((ext_vector_type(8))) short bf16x8;
typedef __attribute__((ext_vector_type(4))) float f32x4;
typedef unsigned long long ull;

__device__ __forceinline__ f32x4 mfma16(bf16x8 a, bf16x8 b, f32x4 c){
  return __builtin_amdgcn_mfma_f32_16x16x32_bf16(a, b, c, 0, 0, 0);
}

// ---------------- helpers ----------------
__device__ __forceinline__ float wave_sum(float v){
  for (int o = 32; o; o >>= 1) v += __shfl_down(v, o);
  return __shfl(v, 0);
}
__device__ __forceinline__ unsigned short f_to_bf(float f){
  unsigned u = __float_as_uint(f);
  unsigned r = (u + 0x7fffu + ((u >> 16) & 1u)) >> 16;
  return (unsigned short)r;
}
__device__ __forceinline__ float2 bf2_to_f2(const unsigned short* p){
  unsigned u = *(const unsigned*)p;
  float2 r;
  r.x = __uint_as_float(u << 16);
  r.y = __uint_as_float(u & 0xffff0000u);
  return r;
}
union UF { ull u; unsigned short s[4]; };
__device__ __forceinline__ ull pkbf4(float a, float b, float c, float d){
  UF x; x.s[0] = f_to_bf(a); x.s[1] = f_to_bf(b); x.s[2] = f_to_bf(c); x.s[3] = f_to_bf(d); return x.u;
}

// fp32 VALU GEMM core (one-off prologue kernels k_penc/k_pca)
__device__ __forceinline__ void gemm_chunk(const float* __restrict__ wrow0, int ldw,
    const unsigned short* xs, float* wt, float acc[4][2]){
  const int t = threadIdx.x, fg = t & 15, bg = t >> 4;
  #pragma unroll 1
  for (int c = 0; c < 8; ++c){
    const int k0 = c*64;
    __syncthreads();
    {
      int i = t*4;
      #pragma unroll
      for (int p = 0; p < 4; ++p, i += 1024){
        const int fr = i >> 6, kk = i & 63;
        float4 v = *(const float4*)(wrow0 + (size_t)fr*ldw + k0 + kk);
        wt[(kk+0)*68 + fr] = v.x;
        wt[(kk+1)*68 + fr] = v.y;
        wt[(kk+2)*68 + fr] = v.z;
        wt[(kk+3)*68 + fr] = v.w;
      }
    }
    __syncthreads();
    const unsigned short* xr0 = xs + (bg*2)*EE + k0;
    const unsigned short* xr1 = xr0 + EE;
    #pragma unroll 8
    for (int k = 0; k < 64; k += 2){
      float w0[4], w1[4];
      *(float4*)w0 = *(const float4*)(wt + (k+0)*68 + fg*4);
      *(float4*)w1 = *(const float4*)(wt + (k+1)*68 + fg*4);
      float2 xv0 = bf2_to_f2(xr0 + k);
      float2 xv1 = bf2_to_f2(xr1 + k);
      #pragma unroll
      for (int i = 0; i < 4; ++i){
        acc[i][0] += w0[i]*xv0.x + w1[i]*xv0.y;
        acc[i][1] += w0[i]*xv1.x + w1[i]*xv1.y;
      }
    }
  }
}

// Stage [B,E] into padded-LDS bf16 with 512 threads; optional pending LN from ybuf.
// If xlnout != null also materialize the LN'd fp32 rows.
__device__ __forceinline__ void stage_x_512(unsigned short* xs,
    const float* __restrict__ xraw, const float* __restrict__ ybuf,
    const float* __restrict__ g, const float* __restrict__ bt, int use_ln,
    float* __restrict__ xlnout){
  if (!use_ln){
    for (int i = threadIdx.x*4; i < BB*EE; i += 2048){
      float4 v = *(const float4*)(xraw + i);
      int r = i >> 9, c = i & 511;
      *(ull*)(xs + r*LDP + c) = pkbf4(v.x, v.y, v.z, v.w);
    }
  } else {
    const int lane = threadIdx.x & 63, wv = threadIdx.x >> 6;
    for (int r = wv*4; r < wv*4 + 4; ++r){
      float vals[8]; float s = 0.f, s2 = 0.f;
      #pragma unroll
      for (int j = 0; j < 8; ++j){
        float v = ybuf[r*EE + lane + j*64];
        vals[j] = v; s += v; s2 += v*v;
      }
      s = wave_sum(s); s2 = wave_sum(s2);
      float m = s * (1.f/EE);
      float inv = rsqrtf(s2*(1.f/EE) - m*m + 1e-5f);
      #pragma unroll
      for (int j = 0; j < 8; ++j){
        int c = lane + j*64;
        float v = (vals[j]-m)*inv*g[c] + bt[c];
        xs[r*LDP + c] = f_to_bf(v);
        if (xlnout) xlnout[r*EE + c] = v;
      }
    }
  }
  __syncthreads();
}

// ---------------- prologue kernels ----------------

__global__ __launch_bounds__(256) void k_init(const float* __restrict__ special,
    float* __restrict__ dseq, float* __restrict__ x,
    float* __restrict__ o2a, float* __restrict__ o2b,
    float* __restrict__ y0, float* __restrict__ y1){
  int idx = blockIdx.x*256 + threadIdx.x;
  if (idx < BB*VV){
    int b = idx >> 13, v = idx & (VV-1);
    dseq[(size_t)b*((TT+1)*VV) + (size_t)TT*VV + v] = (v == 0) ? 1.f : 0.f;
  } else if (idx < BB*VV + BB*EE){
    x[idx - BB*VV] = special[idx & (EE-1)];
  } else if (idx < BB*VV + 2*BB*EE){
    o2a[idx - BB*VV - BB*EE] = 0.f;
  } else if (idx < BB*VV + 3*BB*EE){
    o2b[idx - BB*VV - 2*BB*EE] = 0.f;
  } else if (idx < BB*VV + 4*BB*EE){
    y0[idx - BB*VV - 3*BB*EE] = 0.f;
  } else if (idx < BB*VV + 5*BB*EE){
    y1[idx - BB*VV - 4*BB*EE] = 0.f;
  }
}

__global__ __launch_bounds__(256) void k_penc(const float* __restrict__ enc,
    const float* __restrict__ w, const float* __restrict__ bias, float* __restrict__ venc){
  __shared__ unsigned short xs[BB*EE];
  __shared__ float wt[64*68];
  const int l = blockIdx.x >> 3, et = blockIdx.x & 7;
  for (int i = threadIdx.x; i < BB*EE; i += 256) xs[i] = f_to_bf(enc[i]);
  const int t = threadIdx.x, fg = t & 15, bg = t >> 4;
  const int f0 = et*64;
  const float* wl = w + (size_t)l*3*EE*EE + (size_t)(2*EE + f0)*EE;
  const float* bl = bias + l*3*EE + 2*EE + f0;
  float acc[4][2];
  #pragma unroll
  for (int i = 0; i < 4; ++i){ float bv = bl[fg*4+i]; acc[i][0] = bv; acc[i][1] = bv; }
  gemm_chunk(wl, EE, xs, wt, acc);
  #pragma unroll
  for (int i = 0; i < 4; ++i)
    #pragma unroll
    for (int j = 0; j < 2; ++j)
      venc[(size_t)l*BB*EE + (bg*2+j)*EE + f0 + fg*4 + i] = acc[i][j];
}

__global__ __launch_bounds__(256) void k_pca(const float* __restrict__ venc,
    const float* __restrict__ w, const float* __restrict__ bias, float* __restrict__ cac){
  __shared__ unsigned short xs[BB*EE];
  __shared__ float wt[64*68];
  const int l = blockIdx.x >> 3, et = blockIdx.x & 7;
  const float* vin = venc + (size_t)l*BB*EE;
  for (int i = threadIdx.x; i < BB*EE; i += 256) xs[i] = f_to_bf(vin[i]);
  const int t = threadIdx.x, fg = t & 15, bg = t >> 4;
  const int f0 = et*64;
  const float* wl = w + (size_t)l*EE*EE + (size_t)f0*EE;
  const float* bl = bias + l*EE + f0;
  float acc[4][2];
  #pragma unroll
  for (int i = 0; i < 4; ++i){ float bv = bl[fg*4+i]; acc[i][0] = bv; acc[i][1] = bv; }
  gemm_chunk(wl, EE, xs, wt, acc);
  #pragma unroll
  for (int i = 0; i < 4; ++i)
    #pragma unroll
    for (int j = 0; j < 2; ++j)
      cac[(size_t)l*BB*EE + (bg*2+j)*EE + f0 + fg*4 + i] = acc[i][j];
}

__global__ __launch_bounds__(256) void k_cvt(const float* __restrict__ s,
    unsigned short* __restrict__ d, int n4){
  int i = blockIdx.x*256 + threadIdx.x;
  if (i < n4){
    float4 v = ((const float4*)s)[i];
    ushort4 o;
    o.x = f_to_bf(v.x); o.y = f_to_bf(v.y); o.z = f_to_bf(v.z); o.w = f_to_bf(v.w);
    ((ushort4*)d)[i] = o;
  }
}

__global__ __launch_bounds__(256) void k_embT(const float* __restrict__ emb,
    unsigned short* __restrict__ eT){
  __shared__ unsigned short tl[64][68];
  const int vt = blockIdx.x >> 3, et = blockIdx.x & 7;
  const int v0 = vt*64, e0 = et*64;
  for (int i = threadIdx.x; i < 64*64; i += 256){
    int vv = i >> 6, ee = i & 63;
    tl[vv][ee] = f_to_bf(emb[(size_t)(v0+vv)*EE + e0 + ee]);
  }
  __syncthreads();
  for (int i = threadIdx.x; i < 64*64; i += 256){
    int ee = i >> 6, vv = i & 63;
    eT[(size_t)(e0+ee)*VV + v0 + vv] = tl[vv][ee];
  }
}

// ---------------- per-step kernels ----------------

// A: qkv (head h, 3x64 feats over 6 waves) + attention (head h) + out-projection
// k-split (head h's 64-col slice of W_out) -> atomicAdd partials into o2[l&1].
// grid 8 x 512 threads.
__global__ __launch_bounds__(512) void k_A(
    const float* __restrict__ x, const float* __restrict__ ybuf,
    const float* __restrict__ lng, const float* __restrict__ lnb, int use_ln,
    const unsigned short* __restrict__ Wb, const float* __restrict__ bias,
    const unsigned short* __restrict__ owb_l,
    float* __restrict__ kcl, float* __restrict__ vcl,
    float* __restrict__ xln, float* __restrict__ o2,
    int tpos, int tlen){
  __shared__ unsigned short xs[BB*LDP];
  __shared__ __align__(16) float qs[BB*68];
  __shared__ float att[BB*16];
  const int h = blockIdx.x;
  stage_x_512(xs, x, ybuf, lng, lnb, use_ln, (use_ln && h == 0) ? xln : nullptr);
  const int t = threadIdx.x, wv = t >> 6, lane = t & 63;
  const int lm = lane & 15, kg = lane >> 4;
  const unsigned short* b0r = xs + lm*LDP + kg*8;
  const unsigned short* b1r = xs + (lm+16)*LDP + kg*8;
  if (wv < 6){
    const int c = wv >> 1, half = wv & 1;
    #pragma unroll
    for (int ft = 0; ft < 2; ++ft){
      const int frel_t = (half*2 + ft)*16;
      const unsigned short* ar = Wb + (size_t)(c*EE + h*64 + frel_t + lm)*EE + kg*8;
      f32x4 acc0 = {0.f,0.f,0.f,0.f}, acc1 = {0.f,0.f,0.f,0.f};
      #pragma unroll 4
      for (int ks = 0; ks < 16; ++ks){
        bf16x8 a  = *reinterpret_cast<const bf16x8*>(ar + ks*32);
        bf16x8 b0 = *reinterpret_cast<const bf16x8*>(b0r + ks*32);
        bf16x8 b1 = *reinterpret_cast<const bf16x8*>(b1r + ks*32);
        acc0 = mfma16(a, b0, acc0);
        acc1 = mfma16(a, b1, acc1);
      }
      #pragma unroll
      for (int r = 0; r < 4; ++r){
        const int frel = frel_t + kg*4 + r;
        const float bv = bias[c*EE + h*64 + frel];
        float v0 = acc0[r] + bv, v1 = acc1[r] + bv;
        if (c == 0){
          qs[lm*68 + frel] = v0;
          qs[(lm+16)*68 + frel] = v1;
        } else if (c == 1){
          kcl[((lm*NHD + h)*TT + tpos)*HDD + frel] = v0;
          kcl[(((lm+16)*NHD + h)*TT + tpos)*HDD + frel] = v1;
        } else {
          vcl[((lm*NHD + h)*TT + tpos)*HDD + frel] = v0;
          vcl[(((lm+16)*NHD + h)*TT + tpos)*HDD + frel] = v1;
        }
      }
    }
  }
  __syncthreads();
  // scores: exactly 512 (b,j) items
  {
    const int b = t >> 4, j = t & 15;
    if (j < tlen){
      const float* qrow = qs + b*68;
      const float* krow = kcl + ((b*NHD + h)*TT + j)*HDD;
      float a = 0.f;
      #pragma unroll
      for (int d = 0; d < HDD; d += 4){
        float4 qv = *(const float4*)(qrow + d);
        float4 kv = *(const float4*)(krow + d);
        a += qv.x*kv.x + qv.y*kv.y + qv.z*kv.z + qv.w*kv.w;
      }
      att[b*16 + j] = a*0.125f;
    }
  }
  __syncthreads();
  if (t < 32){
    const int b = t;
    float m = -1e30f;
    for (int j = 0; j < tlen; ++j) m = fmaxf(m, att[b*16 + j]);
    float s = 0.f;
    for (int j = 0; j < tlen; ++j) s += __expf(att[b*16 + j] - m);
    float inv = 1.f/s;
    for (int j = 0; j < tlen; ++j) att[b*16 + j] = __expf(att[b*16 + j] - m)*inv;
  }
  __syncthreads();
  // PV -> o_lds (bf16, pitch OLP); aliases qs (all qs reads complete)
  unsigned short* o_lds = (unsigned short*)qs;
  {
    const int b = t >> 4, d0 = (t & 15)*4;
    float acc[4];
    #pragma unroll
    for (int i = 0; i < 4; ++i) acc[i] = 0.f;
    const float* vrow = vcl + ((b*NHD + h)*TT)*HDD + d0;
    for (int j = 0; j < tlen; ++j){
      const float a = att[b*16 + j];
      float4 v = *(const float4*)(vrow + j*HDD);
      acc[0] += a*v.x; acc[1] += a*v.y; acc[2] += a*v.z; acc[3] += a*v.w;
    }
    *(ull*)(o_lds + b*OLP + d0) = pkbf4(acc[0], acc[1], acc[2], acc[3]);
  }
  __syncthreads();
  // out-projection partial: 8 waves x 4 f-tiles
  const unsigned short* ob0 = o_lds + lm*OLP + kg*8;
  const unsigned short* ob1 = o_lds + (lm+16)*OLP + kg*8;
  #pragma unroll
  for (int ft = 0; ft < 4; ++ft){
    const int f0 = wv*64 + ft*16;
    const unsigned short* ar = owb_l + (size_t)(f0 + lm)*EE + h*HDD + kg*8;
    f32x4 a0 = {0.f,0.f,0.f,0.f}, a1 = {0.f,0.f,0.f,0.f};
    #pragma unroll
    for (int ks = 0; ks < 2; ++ks){
      bf16x8 a  = *reinterpret_cast<const bf16x8*>(ar + ks*32);
      bf16x8 x0 = *reinterpret_cast<const bf16x8*>(ob0 + ks*32);
      bf16x8 x1 = *reinterpret_cast<const bf16x8*>(ob1 + ks*32);
      a0 = mfma16(a, x0, a0);
      a1 = mfma16(a, x1, a1);
    }
    #pragma unroll
    for (int r = 0; r < 4; ++r){
      const int f = f0 + kg*4 + r;
      atomicAdd(&o2[lm*EE + f], a0[r]);
      atomicAdd(&o2[(lm+16)*EE + f], a1[r]);
    }
  }
}

// BC: stage (o2+resid+ob) -> LN1(+cac) -> LN2 -> ffn1 (64 H-feats) -> gelu ->
// ffn2 k-slice partial -> atomicAdd y. y base (LN2out+b2) added atomically by
// per-block 16-col strip. Also zeroes the opposite-parity y and o2 buffers
// (both fully consumed earlier in stream order). grid 32 x 512 threads.
__global__ __launch_bounds__(512) void k_BC(
    const float* __restrict__ o2buf, const float* __restrict__ resid,
    const float* __restrict__ ob, const float* __restrict__ cac,
    const float* __restrict__ g1, const float* __restrict__ b1g,
    const float* __restrict__ g2, const float* __restrict__ b2g,
    const float* __restrict__ b2bias,
    const unsigned short* __restrict__ w1b, const float* __restrict__ b1bias,
    const unsigned short* __restrict__ w2b,
    float* __restrict__ ycur, float* __restrict__ yzero, float* __restrict__ o2zero){
  __shared__ unsigned short xs[BB*LDP];
  __shared__ __align__(16) float rawf[BB*RWP];
  __shared__ unsigned short Hs[BB*OLP];
  const int t = threadIdx.x, blk = blockIdx.x;
  for (int i = t*4; i < BB*EE; i += 2048){
    const int r = i >> 9, c = i & 511;
    float4 a  = *(const float4*)(o2buf + i);
    float4 rr = *(const float4*)(resid + i);
    float4 ov = *(const float4*)(ob + c);
    rawf[r*RWP + c]     = a.x + rr.x + ov.x;
    rawf[r*RWP + c + 1] = a.y + rr.y + ov.y;
    rawf[r*RWP + c + 2] = a.z + rr.z + ov.z;
    rawf[r*RWP + c + 3] = a.w + rr.w + ov.w;
  }
  __syncthreads();
  const int wv = t >> 6, lane = t & 63;
  const int lm = lane & 15, kg = lane >> 4;
  // LN1(+cac) -> LN2 -> xs bf16 ; per-strip y base (atomic, exactly-once)
  {
    const int c0 = lane*4, c1 = 256 + lane*4;
    for (int r = wv*4; r < wv*4 + 4; ++r){
      float v[8];
      *(float4*)(v+0) = *(const float4*)(rawf + r*RWP + c0);
      *(float4*)(v+4) = *(const float4*)(rawf + r*RWP + c1);
      float s = 0.f, s2 = 0.f;
      #pragma unroll
      for (int j = 0; j < 8; ++j){ s += v[j]; s2 += v[j]*v[j]; }
      s = wave_sum(s); s2 = wave_sum(s2);
      float m = s*(1.f/EE), inv = rsqrtf(s2*(1.f/EE) - m*m + 1e-5f);
      float4 ca0 = *(const float4*)(cac + (size_t)r*EE + c0);
      float4 ca1 = *(const float4*)(cac + (size_t)r*EE + c1);
      float nv[8]; float u = 0.f, u2 = 0.f;
      nv[0] = (v[0]-m)*inv*g1[c0+0] + b1g[c0+0] + ca0.x;
      nv[1] = (v[1]-m)*inv*g1[c0+1] + b1g[c0+1] + ca0.y;
      nv[2] = (v[2]-m)*inv*g1[c0+2] + b1g[c0+2] + ca0.z;
      nv[3] = (v[3]-m)*inv*g1[c0+3] + b1g[c0+3] + ca0.w;
      nv[4] = (v[4]-m)*inv*g1[c1+0] + b1g[c1+0] + ca1.x;
      nv[5] = (v[5]-m)*inv*g1[c1+1] + b1g[c1+1] + ca1.y;
      nv[6] = (v[6]-m)*inv*g1[c1+2] + b1g[c1+2] + ca1.z;
      nv[7] = (v[7]-m)*inv*g1[c1+3] + b1g[c1+3] + ca1.w;
      #pragma unroll
      for (int j = 0; j < 8; ++j){ u += nv[j]; u2 += nv[j]*nv[j]; }
      u = wave_sum(u); u2 = wave_sum(u2);
      float m2 = u*(1.f/EE), inv2 = rsqrtf(u2*(1.f/EE) - m2*m2 + 1e-5f);
      float o0 = (nv[0]-m2)*inv2*g2[c0+0] + b2g[c0+0];
      float o1 = (nv[1]-m2)*inv2*g2[c0+1] + b2g[c0+1];
      float o2v = (nv[2]-m2)*inv2*g2[c0+2] + b2g[c0+2];
      float o3 = (nv[3]-m2)*inv2*g2[c0+3] + b2g[c0+3];
      float o4 = (nv[4]-m2)*inv2*g2[c1+0] + b2g[c1+0];
      float o5 = (nv[5]-m2)*inv2*g2[c1+1] + b2g[c1+1];
      float o6 = (nv[6]-m2)*inv2*g2[c1+2] + b2g[c1+2];
      float o7 = (nv[7]-m2)*inv2*g2[c1+3] + b2g[c1+3];
      *(ull*)(xs + r*LDP + c0) = pkbf4(o0, o1, o2v, o3);
      *(ull*)(xs + r*LDP + c1) = pkbf4(o4, o5, o6, o7);
      if ((c0 >> 4) == blk){
        atomicAdd(&ycur[(size_t)r*EE + c0+0], o0 + b2bias[c0+0]);
        atomicAdd(&ycur[(size_t)r*EE + c0+1], o1 + b2bias[c0+1]);
        atomicAdd(&ycur[(size_t)r*EE + c0+2], o2v + b2bias[c0+2]);
        atomicAdd(&ycur[(size_t)r*EE + c0+3], o3 + b2bias[c0+3]);
      }
      if ((c1 >> 4) == blk){
        atomicAdd(&ycur[(size_t)r*EE + c1+0], o4 + b2bias[c1+0]);
        atomicAdd(&ycur[(size_t)r*EE + c1+1], o5 + b2bias[c1+1]);
        atomicAdd(&ycur[(size_t)r*EE + c1+2], o6 + b2bias[c1+2]);
        atomicAdd(&ycur[(size_t)r*EE + c1+3], o7 + b2bias[c1+3]);
      }
    }
  }
  __syncthreads();
  // ffn1 over block's 64 H-features: 8 waves = 4 f-tiles x 2 row-halves
  {
    const int ftile = wv & 3, rh = wv >> 2;
    const int f0w = blk*64 + ftile*16;
    const unsigned short* ar = w1b + (size_t)(f0w + lm)*EE + kg*8;
    const unsigned short* br = xs + (lm + rh*16)*LDP + kg*8;
    f32x4 acc = {0.f,0.f,0.f,0.f};
    #pragma unroll 4
    for (int ks = 0; ks < 16; ++ks){
      bf16x8 a = *reinterpret_cast<const bf16x8*>(ar + ks*32);
      bf16x8 b = *reinterpret_cast<const bf16x8*>(br + ks*32);
      acc = mfma16(a, b, acc);
    }
    const int fbrel = ftile*16 + kg*4;
    float hh[4];
    #pragma unroll
    for (int r = 0; r < 4; ++r){
      const float bv = b1bias[blk*64 + fbrel + r];
      float vv = acc[r] + bv;
      hh[r] = 0.5f*vv*(1.f + erff(vv*0.70710678118654752f));
    }
    *(ull*)(Hs + (lm + rh*16)*OLP + fbrel) = pkbf4(hh[0], hh[1], hh[2], hh[3]);
  }
  __syncthreads();
  // ffn2 partial over this block's 64-k slice: 8 waves x 4 e-tiles -> atomicAdd y
  {
    const unsigned short* hb0 = Hs + lm*OLP + kg*8;
    const unsigned short* hb1 = Hs + (lm+16)*OLP + kg*8;
    #pragma unroll
    for (int et = 0; et < 4; ++et){
      const int e0 = (wv*4 + et)*16;
      const unsigned short* ar = w2b + (size_t)(e0 + lm)*FFD + blk*64 + kg*8;
      f32x4 a0 = {0.f,0.f,0.f,0.f}, a1 = {0.f,0.f,0.f,0.f};
      #pragma unroll
      for (int ks = 0; ks < 2; ++ks){
        bf16x8 a  = *reinterpret_cast<const bf16x8*>(ar + ks*32);
        bf16x8 h0 = *reinterpret_cast<const bf16x8*>(hb0 + ks*32);
        bf16x8 h1 = *reinterpret_cast<const bf16x8*>(hb1 + ks*32);
        a0 = mfma16(a, h0, a0);
        a1 = mfma16(a, h1, a1);
      }
      #pragma unroll
      for (int r = 0; r < 4; ++r){
        const int e = e0 + kg*4 + r;
        atomicAdd(&ycur[lm*EE + e], a0[r]);
        atomicAdd(&ycur[(lm+16)*EE + e], a1[r]);
      }
    }
  }
  // rotation zeroing: opposite-parity y and o2 (consumed earlier in stream order)
  yzero[blk*512 + t] = 0.f;
  o2zero[blk*512 + t] = 0.f;
}

// logits = LN3(y1) @ out_w.T + out_b. grid 128 x 512 (8 waves = 4 f-tiles x 2 row-halves).
__global__ __launch_bounds__(512) void k_logits_m(
    const float* __restrict__ ybuf, const float* __restrict__ lng, const float* __restrict__ lnb,
    const unsigned short* __restrict__ Wb, const float* __restrict__ bias,
    float* __restrict__ logits){
  __shared__ unsigned short xs[BB*LDP];
  stage_x_512(xs, nullptr, ybuf, lng, lnb, 1, nullptr);
  const int t = threadIdx.x, wv = t >> 6, lane = t & 63;
  const int lm = lane & 15, kg = lane >> 4;
  const int ftile = wv & 3, rh = wv >> 2;
  const int f0w = blockIdx.x*64 + ftile*16;
  const unsigned short* ar = Wb + (size_t)(f0w + lm)*EE + kg*8;
  const unsigned short* br = xs + (lm + rh*16)*LDP + kg*8;
  f32x4 acc = {0.f,0.f,0.f,0.f};
  #pragma unroll 4
  for (int ks = 0; ks < 16; ++ks){
    bf16x8 a = *reinterpret_cast<const bf16x8*>(ar + ks*32);
    bf16x8 b = *reinterpret_cast<const bf16x8*>(br + ks*32);
    acc = mfma16(a, b, acc);
  }
  #pragma unroll
  for (int r = 0; r < 4; ++r){
    const int f = f0w + kg*4 + r;
    logits[(size_t)(lm + rh*16)*VV + f] = acc[r] + bias[f];
  }
}

// dual softmax (register-cached logits/gumbel); zeroes x. grid 32 x 512.
__global__ __launch_bounds__(512) void k_softmax(const float* __restrict__ logits,
    const float* __restrict__ gum, float* __restrict__ dseq, float* __restrict__ ddist,
    unsigned short* __restrict__ sbf, float* __restrict__ x, int step){
  const int b = blockIdx.x, t = threadIdx.x, lane = t & 63, wv = t >> 6;
  __shared__ float red[16];
  const float* lr = logits + (size_t)b*VV;
  const float* gr = gum + (size_t)b*VV;
  float lv[16], gv[16];
  #pragma unroll
  for (int g4 = 0; g4 < 4; ++g4){
    const int i0 = t*4 + g4*2048;
    float4 l4 = *(const float4*)(lr + i0);
    float4 g4v = *(const float4*)(gr + i0);
    lv[g4*4+0]=l4.x; lv[g4*4+1]=l4.y; lv[g4*4+2]=l4.z; lv[g4*4+3]=l4.w;
    gv[g4*4+0]=g4v.x; gv[g4*4+1]=g4v.y; gv[g4*4+2]=g4v.z; gv[g4*4+3]=g4v.w;
  }
  float m1 = -1e30f, m2 = -1e30f;
  #pragma unroll
  for (int j = 0; j < 16; ++j){
    m1 = fmaxf(m1, lv[j]);
    m2 = fmaxf(m2, lv[j] + gv[j]);
  }
  for (int o = 32; o; o >>= 1){ m1 = fmaxf(m1, __shfl_down(m1,o)); m2 = fmaxf(m2, __shfl_down(m2,o)); }
  if (lane == 0){ red[wv] = m1; red[8+wv] = m2; }
  __syncthreads();
  m1 = red[0]; m2 = red[8];
  #pragma unroll
  for (int j = 1; j < 8; ++j){ m1 = fmaxf(m1, red[j]); m2 = fmaxf(m2, red[8+j]); }
  __syncthreads();
  float s1 = 0.f, s2 = 0.f;
  #pragma unroll
  for (int j = 0; j < 16; ++j){
    s1 += __expf(lv[j] - m1);
    s2 += __expf(lv[j] + gv[j] - m2);
  }
  for (int o = 32; o; o >>= 1){ s1 += __shfl_down(s1,o); s2 += __shfl_down(s2,o); }
  if (lane == 0){ red[wv] = s1; red[8+wv] = s2; }
  __syncthreads();
  s1 = 0.f; s2 = 0.f;
  #pragma unroll
  for (int j = 0; j < 8; ++j){ s1 += red[j]; s2 += red[8+j]; }
  float r1 = 1.f/s1, r2 = 1.f/s2;
  float* dq = dseq + (size_t)b*((TT+1)*VV) + (size_t)step*VV;
  float* dd = ddist + (size_t)b*VV;
  #pragma unroll
  for (int g4 = 0; g4 < 4; ++g4){
    const int i0 = t*4 + g4*2048;
    float4 ddv, dqv;
    ddv.x = __expf(lv[g4*4+0]-m1)*r1; ddv.y = __expf(lv[g4*4+1]-m1)*r1;
    ddv.z = __expf(lv[g4*4+2]-m1)*r1; ddv.w = __expf(lv[g4*4+3]-m1)*r1;
    dqv.x = __expf(lv[g4*4+0]+gv[g4*4+0]-m2)*r2;
    dqv.y = __expf(lv[g4*4+1]+gv[g4*4+1]-m2)*r2;
    dqv.z = __expf(lv[g4*4+2]+gv[g4*4+2]-m2)*r2;
    dqv.w = __expf(lv[g4*4+3]+gv[g4*4+3]-m2)*r2;
    *(float4*)(dd + i0) = ddv;
    *(float4*)(dq + i0) = dqv;
    *(ull*)(sbf + (size_t)b*VV + i0) = pkbf4(dqv.x, dqv.y, dqv.z, dqv.w);
  }
  x[b*EE + t] = 0.f;   // EE == 512 == blockDim
}

// x += (sample @ emb) * sqrt(E): k-split x16 (K=512), atomics.
// grid 128 x 512 (8 waves = 4 e-tiles x 2 row-halves).
__global__ __launch_bounds__(512) void k_embed_m(
    const unsigned short* __restrict__ eT, const unsigned short* __restrict__ sbf,
    float* __restrict__ x){
  const int t = threadIdx.x, wv = t >> 6, lane = t & 63;
  const int lm = lane & 15, kg = lane >> 4;
  const int etile = wv & 3, rh = wv >> 2;
  const int e0 = (blockIdx.x & 7)*64 + etile*16;
  const int v0 = (blockIdx.x >> 3)*512;
  const unsigned short* ar = eT + (size_t)(e0 + lm)*VV + v0 + kg*8;
  const unsigned short* br = sbf + (size_t)(lm + rh*16)*VV + v0 + kg*8;
  f32x4 acc = {0.f,0.f,0.f,0.f};
  #pragma unroll 4
  for (int ks = 0; ks < 16; ++ks){
    bf16x8 a = *reinterpret_cast<const bf16x8*>(ar + ks*32);
    bf16x8 b = *reinterpret_cast<const bf16x8*>(br + ks*32);
    acc = mfma16(a, b, acc);
  }
  #pragma unroll
  for (int r = 0; r < 4; ++r){
    const int e = e0 + kg*4 + r;
    atomicAdd(&x[(lm + rh*16)*EE + e], acc[r]*SCALE_EMB);
  }
}

// ---------------- host ----------------
extern "C" void kernel_launch(void* const* d_in, const int* in_sizes, int n_in,
                              void* d_out, int out_size, void* d_ws, size_t ws_size,
                              hipStream_t stream){
  (void)in_sizes; (void)n_in; (void)out_size; (void)ws_size;
  const float* enc  = (const float*)d_in[0];
  const float* spec = (const float*)d_in[1];
  const float* embw = (const float*)d_in[2];
  const float* outw = (const float*)d_in[3];
  const float* outb = (const float*)d_in[4];
  const float* gumb = (const float*)d_in[5];
  const float* saqw = (const float*)d_in[6];
  const float* saqb = (const float*)d_in[7];
  const float* saow = (const float*)d_in[8];
  const float* saob = (const float*)d_in[9];
  const float* caqw = (const float*)d_in[10];
  const float* caqb = (const float*)d_in[11];
  const float* caow = (const float*)d_in[12];
  const float* caob = (const float*)d_in[13];
  const float* l1g  = (const float*)d_in[14];
  const float* l1b  = (const float*)d_in[15];
  const float* l2g  = (const float*)d_in[16];
  const float* l2b  = (const float*)d_in[17];
  const float* l3g  = (const float*)d_in[18];
  const float* l3b  = (const float*)d_in[19];
  const float* w1   = (const float*)d_in[20];
  const float* b1   = (const float*)d_in[21];
  const float* w2   = (const float*)d_in[22];
  const float* b2   = (const float*)d_in[23];

  float* dout = (float*)d_out;
  float* dseq = dout;
  float* ddistbase = dout + (size_t)BB*(TT+1)*VV;

  unsigned char* p = (unsigned char*)d_ws;
  auto alloc = [&](size_t bytes) -> void* {
    void* r = (void*)p; p += (bytes + 255) & ~(size_t)255; return r;
  };
  float* x      = (float*)alloc(BB*EE*4);
  float* y0     = (float*)alloc(BB*EE*4);
  float* y1     = (float*)alloc(BB*EE*4);
  float* xln    = (float*)alloc(BB*EE*4);
  float* o2a    = (float*)alloc(BB*EE*4);
  float* o2b    = (float*)alloc(BB*EE*4);
  float* logits = (float*)alloc((size_t)BB*VV*4);
  float* venc   = (float*)alloc((size_t)LL*BB*EE*4);
  float* cac    = (float*)alloc((size_t)LL*BB*EE*4);
  float* kcache = (float*)alloc((size_t)LL*BB*EE*TT*4);
  float* vcache = (float*)alloc((size_t)LL*BB*EE*TT*4);
  unsigned short* sbf   = (unsigned short*)alloc((size_t)BB*VV*2);
  unsigned short* wqkvb = (unsigned short*)alloc((size_t)LL*3*EE*EE*2);
  unsigned short* owb   = (unsigned short*)alloc((size_t)LL*EE*EE*2);
  unsigned short* w1b   = (unsigned short*)alloc((size_t)LL*FFD*EE*2);
  unsigned short* w2b   = (unsigned short*)alloc((size_t)LL*FFD*EE*2);
  unsigned short* outwb = (unsigned short*)alloc((size_t)VV*EE*2);
  unsigned short* eTb   = (unsigned short*)alloc((size_t)EE*VV*2);

  // prologue
  k_init<<<1344, 256, 0, stream>>>(spec, dseq, x, o2a, o2b, y0, y1);
  k_penc<<<32, 256, 0, stream>>>(enc, caqw, caqb, venc);
  k_pca<<<32, 256, 0, stream>>>(venc, caow, caob, cac);
  k_cvt<<<(LL*3*EE*EE/4 + 255)/256, 256, 0, stream>>>(saqw, wqkvb, LL*3*EE*EE/4);
  k_cvt<<<(LL*EE*EE/4 + 255)/256, 256, 0, stream>>>(saow, owb, LL*EE*EE/4);
  k_cvt<<<(LL*FFD*EE/4 + 255)/256, 256, 0, stream>>>(w1, w1b, LL*FFD*EE/4);
  k_cvt<<<(LL*FFD*EE/4 + 255)/256, 256, 0, stream>>>(w2, w2b, LL*FFD*EE/4);
  k_cvt<<<(VV*EE/4 + 255)/256, 256, 0, stream>>>(outw, outwb, VV*EE/4);
  k_embT<<<1024, 256, 0, stream>>>(embw, eTb);

  float* yb[2]  = { y0, y1 };
  float* o2p[2] = { o2a, o2b };

  // 11 launches/step (A fuses qkv+attn+outp; BC fuses ffn1+ffn2)
  for (int step = 0; step < TT; ++step){
    const int tpos = step, tlen = step + 1;
    for (int l = 0; l < LL; ++l){
      const int use_ln = (l > 0);
      const int par = l & 1, opp = par ^ 1;
      const float* lg = l3g + (use_ln ? (l-1)*EE : 0);
      const float* lb = l3b + (use_ln ? (l-1)*EE : 0);
      float* kcl = kcache + (size_t)l*BB*EE*TT;
      float* vcl = vcache + (size_t)l*BB*EE*TT;
      k_A<<<NHD, 512, 0, stream>>>(x, yb[opp], lg, lb, use_ln,
          wqkvb + (size_t)l*3*EE*EE, saqb + (size_t)l*3*EE,
          owb + (size_t)l*EE*EE, kcl, vcl, xln, o2p[par], tpos, tlen);
      k_BC<<<32, 512, 0, stream>>>(o2p[par], use_ln ? xln : x,
          saob + (size_t)l*EE, cac + (size_t)l*BB*EE,
          l1g + l*EE, l1b + l*EE, l2g + l*EE, l2b + l*EE, b2 + l*EE,
          w1b + (size_t)l*FFD*EE, b1 + l*FFD, w2b + (size_t)l*EE*FFD,
          yb[par], yb[opp], o2p[opp]);
    }
    k_logits_m<<<128, 512, 0, stream>>>(yb[1], l3g + 3*EE, l3b + 3*EE, outwb, outb, logits);
    k_softmax<<<32, 512, 0, stream>>>(logits, gumb + (size_t)step*BB*VV, dseq,
        ddistbase + (size_t)step*BB*VV, sbf, x, step);
    k_embed_m<<<128, 512, 0, stream>>>(eTb, sbf, x);
  }
}